// Round 17
// baseline (726.598 us; speedup 1.0000x reference)
//
#include <hip/hip_runtime.h>
#include <hip/hip_fp16.h>
#include <stdint.h>

#define NTOK 4096
#define KCB  16384
#define CAP  256
#define MAXL 8           // per-row per-block LDS compaction slots
#define MARGIN_C 0.02f   // collection margin (~15x worst-case f16 screen error)
#define MARGIN_F 0.02f   // filter margin in rescore

typedef _Float16 f16;
typedef _Float16 f16x8 __attribute__((ext_vector_type(8)));
typedef float f32x4 __attribute__((ext_vector_type(4)));
typedef double f64x4 __attribute__((ext_vector_type(4)));

typedef const __attribute__((address_space(1))) uint32_t* gptr_t;
typedef __attribute__((address_space(3))) uint32_t* lptr_t;
__device__ __forceinline__ void gload_lds16(const void* g, void* l) {
  __builtin_amdgcn_global_load_lds((gptr_t)g, (lptr_t)l, 16, 0, 0);
}

// ---------------- init ----------------
__global__ void k_init(int* cnt, int* bad) {
  int i = blockIdx.x * 256 + threadIdx.x;
  if (i < NTOK) cnt[i] = 0;
  if (blockIdx.x == 0 && threadIdx.x == 0) *bad = 0;
}

// ---------------- build W~^T (320 x 2048) f16 ----------------
__global__ __launch_bounds__(256) void k_build_wT(const float* qc_w, const float* qc_b, f16* wT) {
  __shared__ float tl[64][65];
  int d0 = blockIdx.x * 64, c0 = blockIdx.y * 64;
  int jj = threadIdx.x & 63, i0 = threadIdx.x >> 6;
  for (int ii = 0; ii < 64; ii += 4) {
    int i = ii + i0; int d = d0 + i; int c = c0 + jj;
    float v = 0.f;
    if (c < 256) v = qc_w[(size_t)d * 256 + c];
    else if (c == 256) v = qc_b[d];
    tl[i][jj] = v;
  }
  __syncthreads();
  for (int jj2 = 0; jj2 < 64; jj2 += 4) {
    int j = jj2 + i0; int i = threadIdx.x & 63;
    wT[(size_t)(c0 + j) * 2048 + d0 + i] = (f16)tl[i][j];
  }
}

// ---------------- build x tokens ----------------
__global__ __launch_bounds__(256) void k_build_x(const float* hid, f16* x16, float* x32) {
  __shared__ float tl[64][65];
  int hw0 = blockIdx.x * 64, c0 = blockIdx.y * 64, b = blockIdx.z;
  int jj = threadIdx.x & 63, i0 = threadIdx.x >> 6;
  for (int ii = 0; ii < 64; ii += 4) {
    int i = ii + i0;
    tl[i][jj] = hid[((size_t)b * 256 + c0 + i) * 1024 + hw0 + jj];
  }
  __syncthreads();
  for (int jj2 = 0; jj2 < 64; jj2 += 4) {
    int j = jj2 + i0; int i = threadIdx.x & 63;
    int t = b * 1024 + hw0 + j; float v = tl[i][j];
    x32[(size_t)t * 256 + c0 + i] = v;
    x16[(size_t)t * 320 + c0 + i] = (f16)v;
  }
  if (blockIdx.y == 0) {
    int tb = b * 1024 + hw0;
    for (int q = 0; q < 16; q++) {
      int idx2 = threadIdx.x * 16 + q;
      int tl2 = idx2 >> 6, p = idx2 & 63;
      x16[(size_t)(tb + tl2) * 320 + 256 + p] = (p == 0) ? (f16)1.0f : (f16)0.0f;
    }
  }
}

// ---------------- proj via f64 MFMA with runtime layout self-test (VERIFIED r14/r15) ----------------
__global__ __launch_bounds__(256) void k_proj_mfma(const float* x32, const float* qc_w, const float* qc_b,
                                                   double* h64, int* bad) {
  __shared__ double At[32][66];
  __shared__ double Bt[32][130];
  int d0 = blockIdx.x * 128, t0 = blockIdx.y * 64;
  int tid = threadIdx.x, wid = tid >> 6, lane = tid & 63;
  int cl = lane & 15, g = lane >> 4;

  double ta1 = (double)cl;
  double tb1 = (g == 0) ? 1.0 : 0.0;
  f64x4 tc1 = {0.0, 0.0, 0.0, 0.0};
  tc1 = __builtin_amdgcn_mfma_f64_16x16x4f64(ta1, tb1, tc1, 0, 0, 0);
  double ta2 = (g == 0) ? 1.0 : 0.0;
  double tb2 = (g == 0) ? (double)cl : 0.0;
  f64x4 tc2 = {0.0, 0.0, 0.0, 0.0};
  tc2 = __builtin_amdgcn_mfma_f64_16x16x4f64(ta2, tb2, tc2, 0, 0, 0);
  bool std_ok = true, alt_ok = true, col_ok = true;
#pragma unroll
  for (int r = 0; r < 4; r++) {
    std_ok = std_ok && (tc1[r] == (double)(4 * g + r));
    alt_ok = alt_ok && (tc1[r] == (double)(g + 4 * r));
    col_ok = col_ok && (tc2[r] == (double)cl);
  }
  unsigned long long mstd = __ballot(std_ok), malt = __ballot(alt_ok), mcol = __ballot(col_ok);
  bool all_std = (mstd == ~0ull), all_alt = (malt == ~0ull), all_col = (mcol == ~0ull);
  bool good = (all_std || all_alt) && all_col;
  if (!good) { if (tid == 0) atomicOr(bad, 1); return; }
  int use_alt = all_alt ? 1 : 0;

  int t_a = tid & 63, ka = (tid >> 6) * 8;
  int d_b = tid & 127, kb = (tid >> 7) * 16;
  f32x4 ra0, ra1, rb0, rb1, rb2, rb3;
  auto ldregs = [&](int kc) {
    ra0 = *(const f32x4*)(x32 + (size_t)(t0 + t_a) * 256 + kc + ka);
    ra1 = *(const f32x4*)(x32 + (size_t)(t0 + t_a) * 256 + kc + ka + 4);
    rb0 = *(const f32x4*)(qc_w + (size_t)(d0 + d_b) * 256 + kc + kb);
    rb1 = *(const f32x4*)(qc_w + (size_t)(d0 + d_b) * 256 + kc + kb + 4);
    rb2 = *(const f32x4*)(qc_w + (size_t)(d0 + d_b) * 256 + kc + kb + 8);
    rb3 = *(const f32x4*)(qc_w + (size_t)(d0 + d_b) * 256 + kc + kb + 12);
  };
  ldregs(0);

  f64x4 acc[4][2];
#pragma unroll
  for (int i = 0; i < 4; i++)
#pragma unroll
    for (int j = 0; j < 2; j++) acc[i][j] = (f64x4)0.0;

  for (int c = 0; c < 8; c++) {
    __syncthreads();
#pragma unroll
    for (int e = 0; e < 4; e++) {
      At[ka + e][t_a] = (double)ra0[e];
      At[ka + 4 + e][t_a] = (double)ra1[e];
      Bt[kb + e][d_b] = (double)rb0[e];
      Bt[kb + 4 + e][d_b] = (double)rb1[e];
      Bt[kb + 8 + e][d_b] = (double)rb2[e];
      Bt[kb + 12 + e][d_b] = (double)rb3[e];
    }
    __syncthreads();
    if (c < 7) ldregs((c + 1) * 32);
#pragma unroll
    for (int k4 = 0; k4 < 8; k4++) {
      int k = k4 * 4 + g;
      double a[4], b[2];
#pragma unroll
      for (int i = 0; i < 4; i++) a[i] = At[k][16 * i + cl];
#pragma unroll
      for (int j = 0; j < 2; j++) b[j] = Bt[k][32 * wid + 16 * j + cl];
#pragma unroll
      for (int i = 0; i < 4; i++)
#pragma unroll
        for (int j = 0; j < 2; j++)
          acc[i][j] = __builtin_amdgcn_mfma_f64_16x16x4f64(a[i], b[j], acc[i][j], 0, 0, 0);
    }
  }
#pragma unroll
  for (int i = 0; i < 4; i++)
#pragma unroll
    for (int j = 0; j < 2; j++) {
      int d = d0 + 32 * wid + 16 * j + cl;
      double bias = (double)qc_b[d];
#pragma unroll
      for (int r = 0; r < 4; r++) {
        int row = use_alt ? (g + 4 * r) : (4 * g + r);
        int t = t0 + 16 * i + row;
        h64[(size_t)t * 2048 + d] = acc[i][j][r] + bias;
      }
    }
}

// ---------------- fallback proj (proj2b VERIFIED r8-r13) — runs only if self-test tripped ----------------
__global__ __launch_bounds__(256) void k_proj_fb(const float* x32, const float* qc_w, const float* qc_b,
                                                 double* h64, const int* bad) {
  if (*bad == 0) return;
  __shared__ double At[16][128];
  __shared__ double Bt[16][16][9];
  int t0 = blockIdx.y * 128, d0 = blockIdx.x * 128;
  int tid = threadIdx.x;
  int tr = tid >> 4, dc = tid & 15;
  int srow = tid & 127, kh = (tid >> 7) * 8;
  int sg = srow >> 3, se = srow & 7;
  const float* pA = x32 + (size_t)(t0 + srow) * 256 + kh;
  const float* pB = qc_w + (size_t)(d0 + srow) * 256 + kh;
  f32x4 a0 = *(const f32x4*)pA, a1 = *(const f32x4*)(pA + 4);
  f32x4 b0 = *(const f32x4*)pB, b1 = *(const f32x4*)(pB + 4);
  double acc[8][8] = {};
  for (int kk = 0; kk < 256; kk += 16) {
    __syncthreads();
#pragma unroll
    for (int j = 0; j < 4; j++) {
      At[kh + j][srow] = (double)a0[j]; At[kh + 4 + j][srow] = (double)a1[j];
      Bt[kh + j][sg][se] = (double)b0[j]; Bt[kh + 4 + j][sg][se] = (double)b1[j];
    }
    __syncthreads();
    if (kk + 16 < 256) {
      a0 = *(const f32x4*)(pA + kk + 16); a1 = *(const f32x4*)(pA + kk + 20);
      b0 = *(const f32x4*)(pB + kk + 16); b1 = *(const f32x4*)(pB + kk + 20);
    }
#pragma unroll
    for (int k = 0; k < 16; k++) {
      double a[8], b[8];
#pragma unroll
      for (int j = 0; j < 8; j++) a[j] = At[k][tr * 8 + j];
#pragma unroll
      for (int j = 0; j < 8; j++) b[j] = Bt[k][dc][j];
#pragma unroll
      for (int i = 0; i < 8; i++)
#pragma unroll
        for (int j = 0; j < 8; j++)
          acc[i][j] = fma(a[i], b[j], acc[i][j]);
    }
  }
#pragma unroll
  for (int i = 0; i < 8; i++)
#pragma unroll
    for (int j = 0; j < 8; j++) {
      int col = d0 + dc * 8 + j;
      h64[(size_t)(t0 + tr * 8 + i) * 2048 + col] = acc[i][j] + (double)qc_b[col];
    }
}

// ---------------- P' GEMM fused with codebook norms (VERIFIED r7-r16) ----------------
__global__ __launch_bounds__(256) void k_pgemm4(const float* cb, const f16* wT, f16* P16kt,
                                                double* inv64, float* inv32) {
  __shared__ f16 Al[2][64][32];
  __shared__ f16 Bl[2][160][32];
  __shared__ double nsum[64][4];
  __shared__ double invsh[64];
  int j0 = blockIdx.x * 64;
  int c0 = blockIdx.y * 160;
  int tid = threadIdx.x, wid = tid >> 6, lane = tid & 63;
  int cl = lane & 15, g = lane >> 4;
  f32x4 acc[10];
#pragma unroll
  for (int n = 0; n < 10; n++) acc[n] = (f32x4)0.0f;
  int arow = tid & 63, aseg = tid >> 6;
  double s2 = 0.0;

  auto aload = [&](int kk, f32x4& v0, f32x4& v1) {
    v0 = *(const f32x4*)(cb + (size_t)(j0 + arow) * 2048 + kk + aseg * 8);
    v1 = *(const f32x4*)(cb + (size_t)(j0 + arow) * 2048 + kk + aseg * 8 + 4);
  };
  auto addnorm = [&](f32x4 v0, f32x4 v1) {
#pragma unroll
    for (int e = 0; e < 4; e++) {
      s2 += (double)v0[e] * (double)v0[e];
      s2 += (double)v1[e] * (double)v1[e];
    }
  };
  auto awrite = [&](int buf, f32x4 v0, f32x4 v1) {
    f16x8 h;
#pragma unroll
    for (int e = 0; e < 4; e++) { h[e] = (f16)v0[e]; h[4 + e] = (f16)v1[e]; }
    int sp = aseg ^ ((arow >> 1) & 3);
    *(f16x8*)((char*)&Al[buf][arow][0] + sp * 16) = h;
  };
  auto stageB = [&](int kk, int buf) {
#pragma unroll
    for (int i = 0; i < 3; i++) {
      int g2 = wid + 4 * i;
      if (g2 < 10) {
        int r0 = 16 * g2;
        int rl = r0 + (lane >> 2);
        int sl = (lane & 3) ^ ((rl >> 1) & 3);
        gload_lds16(wT + (size_t)(c0 + rl) * 2048 + kk + sl * 8, &Bl[buf][r0][0]);
      }
    }
  };
  auto rdA = [&](int buf, int r, int sg2) -> f16x8 {
    return *(const f16x8*)((const char*)&Al[buf][0][0] + r * 64 + ((sg2 ^ ((r >> 1) & 3)) << 4));
  };
  auto rdB = [&](int buf, int r, int sg2) -> f16x8 {
    return *(const f16x8*)((const char*)&Bl[buf][0][0] + r * 64 + ((sg2 ^ ((r >> 1) & 3)) << 4));
  };

  { f32x4 v0, v1; aload(0, v0, v1); addnorm(v0, v1); awrite(0, v0, v1); }
  stageB(0, 0);
  asm volatile("s_waitcnt vmcnt(0)" ::: "memory");
  __syncthreads();
  for (int s = 0; s < 64; s++) {
    int buf = s & 1;
    f32x4 v0, v1;
    if (s < 63) { aload((s + 1) * 32, v0, v1); stageB((s + 1) * 32, buf ^ 1); }
    f16x8 av = rdA(buf, 16 * wid + cl, g);
#pragma unroll
    for (int n = 0; n < 10; n++) {
      f16x8 bv = rdB(buf, 16 * n + cl, g);
      acc[n] = __builtin_amdgcn_mfma_f32_16x16x32_f16(av, bv, acc[n], 0, 0, 0);
    }
    if (s < 63) { addnorm(v0, v1); awrite(buf ^ 1, v0, v1); }
    asm volatile("s_waitcnt vmcnt(0)" ::: "memory");
    __syncthreads();
  }
  nsum[arow][aseg] = s2;
  __syncthreads();
  if (tid < 64) {
    double t = nsum[tid][0] + nsum[tid][1] + nsum[tid][2] + nsum[tid][3];
    double nn = sqrt(t); nn = fmax(nn, 1e-12);
    double iv = 1.0 / nn;
    invsh[tid] = iv;
    if (blockIdx.y == 0) { inv64[j0 + tid] = iv; inv32[j0 + tid] = (float)iv; }
  }
  __syncthreads();
#pragma unroll
  for (int r = 0; r < 4; r++) {
    int rloc = 16 * wid + 4 * g + r;
    int row = j0 + rloc;
    float sc = (float)invsh[rloc];
#pragma unroll
    for (int n = 0; n < 10; n++) {
      int c = c0 + 16 * n + cl;
      int ks = c >> 5;
      int sl = ((c & 31) >> 3) ^ ((row >> 1) & 3);
      P16kt[(((size_t)ks * KCB + row) << 5) + (sl << 3) + (c & 7)] = (f16)(acc[n][r] * sc);
    }
  }
}

// ---------------- screen v13: 256x256 tile, 512 threads, DOUBLE buffer m97-style, 2 blocks/CU ----------------
// Grid 1024, XCD swizzle: xcd = bid&7 owns code-blocks [8*xcd, 8*xcd+8).
__global__ __launch_bounds__(512, 4) void k_screen13(const f16* x16, const f16* P16kt,
                                                     int* cnt, float* cand_v, int* cand_i) {
  __shared__ f16 Al[2][256][32];
  __shared__ f16 Bl[2][256][32];
  __shared__ float smx[256][4];
  int bid = blockIdx.x;
  int nb = ((bid & 7) << 3) | ((bid >> 3) & 7);    // code-block 0..63 (256 codes each)
  int tb = bid >> 6;                                // token-block 0..15 (256 tokens each)
  int n0 = nb * 256, t0 = tb * 256;
  int tid = threadIdx.x, wid = tid >> 6, lane = tid & 63;
  int wr = wid >> 2, wc = wid & 3;                  // 2 x 4 wave grid; wave tile 128 x 64
  int cl = lane & 15, g = lane >> 4;
  f32x4 acc[8][4];
#pragma unroll
  for (int m = 0; m < 8; m++)
#pragma unroll
    for (int n = 0; n < 4; n++) acc[m][n] = (f32x4)0.0f;

  auto stageA = [&](int ks, int buf) {
#pragma unroll
    for (int i = 0; i < 2; i++) {
      int r0 = 32 * wid + 16 * i;
      int rl = r0 + (lane >> 2);
      int sl = (lane & 3) ^ ((rl >> 1) & 3);
      gload_lds16(x16 + (size_t)(t0 + rl) * 320 + ks * 32 + sl * 8, &Al[buf][r0][0]);
    }
  };
  auto stageB = [&](int ks, int buf) {
    const f16* src = P16kt + (((size_t)ks * KCB + n0) << 5) + wid * 1024 + lane * 8;
    gload_lds16(src, &Bl[buf][wid * 32][0]);
    gload_lds16(src + 512, &Bl[buf][wid * 32 + 16][0]);
  };
  auto rdA = [&](int buf, int r, int sg) -> f16x8 {
    return *(const f16x8*)((const char*)&Al[buf][0][0] + r * 64 + ((sg ^ ((r >> 1) & 3)) << 4));
  };
  auto rdB = [&](int buf, int r, int sg) -> f16x8 {
    return *(const f16x8*)((const char*)&Bl[buf][0][0] + r * 64 + ((sg ^ ((r >> 1) & 3)) << 4));
  };

  stageA(0, 0); stageB(0, 0);
  __syncthreads();
#pragma unroll
  for (int s = 0; s < 10; s++) {
    const int buf = s & 1;
    if (s < 9) { stageA(s + 1, buf ^ 1); stageB(s + 1, buf ^ 1); }
    f16x8 av[8], bv[4];
#pragma unroll
    for (int m = 0; m < 8; m++) av[m] = rdA(buf, 128 * wr + 16 * m + cl, g);
#pragma unroll
    for (int n = 0; n < 4; n++) bv[n] = rdB(buf, 64 * wc + 16 * n + cl, g);
    __builtin_amdgcn_s_setprio(1);
#pragma unroll
    for (int m = 0; m < 8; m++)
#pragma unroll
      for (int n = 0; n < 4; n++)
        acc[m][n] = __builtin_amdgcn_mfma_f32_16x16x32_f16(av[m], bv[n], acc[m][n], 0, 0, 0);
    __builtin_amdgcn_s_setprio(0);
    __syncthreads();   // drains vmcnt+lgkmcnt: next-buffer data ready, this-buffer reads done
  }

  // ---- epilogue phase 1: block-local row max (per wave-col partial, then combined)
#pragma unroll
  for (int m = 0; m < 8; m++) {
#pragma unroll
    for (int r = 0; r < 4; r++) {
      float v = -3.4e38f;
#pragma unroll
      for (int n = 0; n < 4; n++) v = fmaxf(v, acc[m][n][r]);
      v = fmaxf(v, __shfl_xor(v, 1));
      v = fmaxf(v, __shfl_xor(v, 2));
      v = fmaxf(v, __shfl_xor(v, 4));
      v = fmaxf(v, __shfl_xor(v, 8));
      if (cl == 0) smx[128 * wr + 16 * m + 4 * g + r][wc] = v;
    }
  }
  __syncthreads();

  // ---- epilogue phase 2: LDS-compacted collection (overlay on dead Al buffer)
  uint32_t* lcnt = (uint32_t*)(&Al[0][0][0]);       // 256 u32
  float*    lval = (float*)(lcnt + 256);            // 256*MAXL f32
  int*      lidx = (int*)(lval + 256 * MAXL);       // 256*MAXL i32
  if (tid < 256) lcnt[tid] = 0;
  __syncthreads();

#pragma unroll
  for (int m = 0; m < 8; m++) {
#pragma unroll
    for (int r = 0; r < 4; r++) {
      int rloc = 128 * wr + 16 * m + 4 * g + r;
      float lim = fmaxf(fmaxf(smx[rloc][0], smx[rloc][1]), fmaxf(smx[rloc][2], smx[rloc][3])) - MARGIN_C;
#pragma unroll
      for (int n = 0; n < 4; n++) {
        float vv = acc[m][n][r];
        if (vv >= lim) {
          uint32_t p = atomicAdd(&lcnt[rloc], 1u);
          int code = n0 + 64 * wc + 16 * n + cl;
          if (p < MAXL) { lval[rloc * MAXL + p] = vv; lidx[rloc * MAXL + p] = code; }
          else {
            int slot = atomicAdd(&cnt[t0 + rloc], 1);
            if (slot < CAP) { cand_v[(t0 + rloc) * CAP + slot] = vv; cand_i[(t0 + rloc) * CAP + slot] = code; }
          }
        }
      }
    }
  }
  __syncthreads();

  // ---- epilogue phase 3: one global atomic per row, bulk copy
  if (tid < 256) {
    int lc = (int)lcnt[tid]; if (lc > MAXL) lc = MAXL;
    if (lc > 0) {
      int row = t0 + tid;
      int base = atomicAdd(&cnt[row], lc);
      for (int i = 0; i < lc; i++) {
        int slot = base + i;
        if (slot < CAP) {
          cand_v[row * CAP + slot] = lval[tid * MAXL + i];
          cand_i[row * CAP + slot] = lidx[tid * MAXL + i];
        }
      }
    }
  }
}

// ---------------- rescore v3: one wave per token, no LDS / no barriers (VERIFIED r14-r16) ----------------
__global__ __launch_bounds__(64) void k_rescore3(const double* h64, const float* cb, const double* inv64,
                                                 const int* cnt, const float* cand_v, const int* cand_i,
                                                 float* idxf, int* idxi) {
  int t = blockIdx.x;
  int lane = threadIdx.x;
  int ctot = cnt[t];
  double bV = -1e300; int bI = 0x7fffffff;
  const double* hrow = h64 + (size_t)t * 2048;
  if (ctot <= CAP) {
    float gm = -3.4e38f;
    for (int c = lane; c < ctot; c += 64) gm = fmaxf(gm, cand_v[t * CAP + c]);
#pragma unroll
    for (int o = 32; o; o >>= 1) gm = fmaxf(gm, __shfl_xor(gm, o));
    float lim = gm - MARGIN_F;
    for (int c = 0; c < ctot; c++) {
      float v = cand_v[t * CAP + c];
      if (v < lim) continue;
      int code = cand_i[t * CAP + c];
      const float* crow = cb + (size_t)code * 2048;
      double p = 0.0;
#pragma unroll
      for (int e = 0; e < 32; e++) {
        int d = lane + 64 * e;
        p = fma(hrow[d], (double)crow[d], p);
      }
#pragma unroll
      for (int o = 32; o; o >>= 1) p += __shfl_xor(p, o);
      double sv = p * inv64[code];
      if (sv > bV || (sv == bV && code < bI)) { bV = sv; bI = code; }
    }
  } else {
    for (int code = 0; code < KCB; code++) {
      const float* crow = cb + (size_t)code * 2048;
      double p = 0.0;
      for (int e = 0; e < 32; e++) {
        int d = lane + 64 * e;
        p = fma(hrow[d], (double)crow[d], p);
      }
      for (int o = 32; o; o >>= 1) p += __shfl_xor(p, o);
      double sv = p * inv64[code];
      if (sv > bV || (sv == bV && code < bI)) { bV = sv; bI = code; }
    }
  }
  if (lane == 0) { idxi[t] = bI; idxf[t] = (float)bI; }
}

// ---------------- gather quant output ----------------
__global__ __launch_bounds__(256) void k_quant(const float* cb, const float* inv32, const int* idxi, float* out0) {
  int hw = blockIdx.x * 256 + threadIdx.x;
  int d = blockIdx.y, b = blockIdx.z;
  int t = b * 1024 + hw;
  int row = idxi[t];
  out0[((size_t)b * 2048 + d) * 1024 + hw] = cb[(size_t)row * 2048 + d] * inv32[row];
}

extern "C" void kernel_launch(void* const* d_in, const int* in_sizes, int n_in,
                              void* d_out, int out_size, void* d_ws, size_t ws_size,
                              hipStream_t stream) {
  const float* hid = (const float*)d_in[0];
  const float* cb  = (const float*)d_in[1];
  const float* qw  = (const float*)d_in[2];
  const float* qb  = (const float*)d_in[3];
  float* out = (float*)d_out;  // [4*2048*1024 quant][4096 idx-as-float]

  char* w = (char*)d_ws;
  size_t off = 0;
  auto alloc = [&](size_t bytes) -> void* {
    void* p = w + off;
    off += (bytes + 255) & ~(size_t)255;
    return p;
  };
  double* h64   = (double*)alloc((size_t)NTOK * 2048 * 8);
  f16*    x16   = (f16*)   alloc((size_t)NTOK * 320 * 2);
  float*  x32   = (float*) alloc((size_t)NTOK * 256 * 4);
  f16*    wT    = (f16*)   alloc((size_t)320 * 2048 * 2);
  f16*    P16kt = (f16*)   alloc((size_t)10 * KCB * 32 * 2);
  double* inv64 = (double*)alloc((size_t)KCB * 8);
  float*  inv32 = (float*) alloc((size_t)KCB * 4);
  int*    cnt   = (int*)   alloc((size_t)NTOK * 4);
  float*  cand_v= (float*) alloc((size_t)NTOK * CAP * 4);
  int*    cand_i= (int*)   alloc((size_t)NTOK * CAP * 4);
  int*    idxi  = (int*)   alloc((size_t)NTOK * 4);
  int*    bad   = (int*)   alloc(256);

  k_init<<<16, 256, 0, stream>>>(cnt, bad);
  k_build_wT<<<dim3(32, 5), 256, 0, stream>>>(qw, qb, wT);
  k_build_x<<<dim3(16, 4, 4), 256, 0, stream>>>(hid, x16, x32);
  k_proj_mfma<<<dim3(16, 64), 256, 0, stream>>>(x32, qw, qb, h64, bad);
  k_proj_fb<<<dim3(16, 32), 256, 0, stream>>>(x32, qw, qb, h64, bad);
  k_pgemm4<<<dim3(256, 2), 256, 0, stream>>>(cb, wT, P16kt, inv64, inv32);
  k_screen13<<<1024, 512, 0, stream>>>(x16, P16kt, cnt, cand_v, cand_i);
  k_rescore3<<<NTOK, 64, 0, stream>>>(h64, cb, inv64, cnt, cand_v, cand_i, out + 8388608, idxi);
  k_quant<<<dim3(4, 2048, 4), 256, 0, stream>>>(cb, inv32, idxi, out);
}

// Round 18
// 359.357 us; speedup vs baseline: 2.0219x; 2.0219x over previous
//
#include <hip/hip_runtime.h>
#include <hip/hip_fp16.h>
#include <stdint.h>

#define NTOK 4096
#define KCB  16384
#define CAP  256
#define MAXL 8           // per-row per-block LDS compaction slots
#define MARGIN_C 0.02f   // collection margin (~15x worst-case f16 screen error)
#define MARGIN_F 0.02f   // filter margin in rescore

typedef _Float16 f16;
typedef _Float16 f16x8 __attribute__((ext_vector_type(8)));
typedef float f32x4 __attribute__((ext_vector_type(4)));
typedef double f64x4 __attribute__((ext_vector_type(4)));

typedef const __attribute__((address_space(1))) uint32_t* gptr_t;
typedef __attribute__((address_space(3))) uint32_t* lptr_t;
__device__ __forceinline__ void gload_lds16(const void* g, void* l) {
  __builtin_amdgcn_global_load_lds((gptr_t)g, (lptr_t)l, 16, 0, 0);
}

// ---------------- init ----------------
__global__ void k_init(int* cnt, int* bad) {
  int i = blockIdx.x * 256 + threadIdx.x;
  if (i < NTOK) cnt[i] = 0;
  if (blockIdx.x == 0 && threadIdx.x == 0) *bad = 0;
}

// ---------------- build W~^T (320 x 2048) f16 ----------------
__global__ __launch_bounds__(256) void k_build_wT(const float* qc_w, const float* qc_b, f16* wT) {
  __shared__ float tl[64][65];
  int d0 = blockIdx.x * 64, c0 = blockIdx.y * 64;
  int jj = threadIdx.x & 63, i0 = threadIdx.x >> 6;
  for (int ii = 0; ii < 64; ii += 4) {
    int i = ii + i0; int d = d0 + i; int c = c0 + jj;
    float v = 0.f;
    if (c < 256) v = qc_w[(size_t)d * 256 + c];
    else if (c == 256) v = qc_b[d];
    tl[i][jj] = v;
  }
  __syncthreads();
  for (int jj2 = 0; jj2 < 64; jj2 += 4) {
    int j = jj2 + i0; int i = threadIdx.x & 63;
    wT[(size_t)(c0 + j) * 2048 + d0 + i] = (f16)tl[i][j];
  }
}

// ---------------- build x tokens ----------------
__global__ __launch_bounds__(256) void k_build_x(const float* hid, f16* x16, float* x32) {
  __shared__ float tl[64][65];
  int hw0 = blockIdx.x * 64, c0 = blockIdx.y * 64, b = blockIdx.z;
  int jj = threadIdx.x & 63, i0 = threadIdx.x >> 6;
  for (int ii = 0; ii < 64; ii += 4) {
    int i = ii + i0;
    tl[i][jj] = hid[((size_t)b * 256 + c0 + i) * 1024 + hw0 + jj];
  }
  __syncthreads();
  for (int jj2 = 0; jj2 < 64; jj2 += 4) {
    int j = jj2 + i0; int i = threadIdx.x & 63;
    int t = b * 1024 + hw0 + j; float v = tl[i][j];
    x32[(size_t)t * 256 + c0 + i] = v;
    x16[(size_t)t * 320 + c0 + i] = (f16)v;
  }
  if (blockIdx.y == 0) {
    int tb = b * 1024 + hw0;
    for (int q = 0; q < 16; q++) {
      int idx2 = threadIdx.x * 16 + q;
      int tl2 = idx2 >> 6, p = idx2 & 63;
      x16[(size_t)(tb + tl2) * 320 + 256 + p] = (p == 0) ? (f16)1.0f : (f16)0.0f;
    }
  }
}

// ---------------- proj via f64 MFMA with runtime layout self-test (VERIFIED r14-r16) ----------------
__global__ __launch_bounds__(256) void k_proj_mfma(const float* x32, const float* qc_w, const float* qc_b,
                                                   double* h64, int* bad) {
  __shared__ double At[32][66];
  __shared__ double Bt[32][130];
  int d0 = blockIdx.x * 128, t0 = blockIdx.y * 64;
  int tid = threadIdx.x, wid = tid >> 6, lane = tid & 63;
  int cl = lane & 15, g = lane >> 4;

  double ta1 = (double)cl;
  double tb1 = (g == 0) ? 1.0 : 0.0;
  f64x4 tc1 = {0.0, 0.0, 0.0, 0.0};
  tc1 = __builtin_amdgcn_mfma_f64_16x16x4f64(ta1, tb1, tc1, 0, 0, 0);
  double ta2 = (g == 0) ? 1.0 : 0.0;
  double tb2 = (g == 0) ? (double)cl : 0.0;
  f64x4 tc2 = {0.0, 0.0, 0.0, 0.0};
  tc2 = __builtin_amdgcn_mfma_f64_16x16x4f64(ta2, tb2, tc2, 0, 0, 0);
  bool std_ok = true, alt_ok = true, col_ok = true;
#pragma unroll
  for (int r = 0; r < 4; r++) {
    std_ok = std_ok && (tc1[r] == (double)(4 * g + r));
    alt_ok = alt_ok && (tc1[r] == (double)(g + 4 * r));
    col_ok = col_ok && (tc2[r] == (double)cl);
  }
  unsigned long long mstd = __ballot(std_ok), malt = __ballot(alt_ok), mcol = __ballot(col_ok);
  bool all_std = (mstd == ~0ull), all_alt = (malt == ~0ull), all_col = (mcol == ~0ull);
  bool good = (all_std || all_alt) && all_col;
  if (!good) { if (tid == 0) atomicOr(bad, 1); return; }
  int use_alt = all_alt ? 1 : 0;

  int t_a = tid & 63, ka = (tid >> 6) * 8;
  int d_b = tid & 127, kb = (tid >> 7) * 16;
  f32x4 ra0, ra1, rb0, rb1, rb2, rb3;
  auto ldregs = [&](int kc) {
    ra0 = *(const f32x4*)(x32 + (size_t)(t0 + t_a) * 256 + kc + ka);
    ra1 = *(const f32x4*)(x32 + (size_t)(t0 + t_a) * 256 + kc + ka + 4);
    rb0 = *(const f32x4*)(qc_w + (size_t)(d0 + d_b) * 256 + kc + kb);
    rb1 = *(const f32x4*)(qc_w + (size_t)(d0 + d_b) * 256 + kc + kb + 4);
    rb2 = *(const f32x4*)(qc_w + (size_t)(d0 + d_b) * 256 + kc + kb + 8);
    rb3 = *(const f32x4*)(qc_w + (size_t)(d0 + d_b) * 256 + kc + kb + 12);
  };
  ldregs(0);

  f64x4 acc[4][2];
#pragma unroll
  for (int i = 0; i < 4; i++)
#pragma unroll
    for (int j = 0; j < 2; j++) acc[i][j] = (f64x4)0.0;

  for (int c = 0; c < 8; c++) {
    __syncthreads();
#pragma unroll
    for (int e = 0; e < 4; e++) {
      At[ka + e][t_a] = (double)ra0[e];
      At[ka + 4 + e][t_a] = (double)ra1[e];
      Bt[kb + e][d_b] = (double)rb0[e];
      Bt[kb + 4 + e][d_b] = (double)rb1[e];
      Bt[kb + 8 + e][d_b] = (double)rb2[e];
      Bt[kb + 12 + e][d_b] = (double)rb3[e];
    }
    __syncthreads();
    if (c < 7) ldregs((c + 1) * 32);
#pragma unroll
    for (int k4 = 0; k4 < 8; k4++) {
      int k = k4 * 4 + g;
      double a[4], b[2];
#pragma unroll
      for (int i = 0; i < 4; i++) a[i] = At[k][16 * i + cl];
#pragma unroll
      for (int j = 0; j < 2; j++) b[j] = Bt[k][32 * wid + 16 * j + cl];
#pragma unroll
      for (int i = 0; i < 4; i++)
#pragma unroll
        for (int j = 0; j < 2; j++)
          acc[i][j] = __builtin_amdgcn_mfma_f64_16x16x4f64(a[i], b[j], acc[i][j], 0, 0, 0);
    }
  }
#pragma unroll
  for (int i = 0; i < 4; i++)
#pragma unroll
    for (int j = 0; j < 2; j++) {
      int d = d0 + 32 * wid + 16 * j + cl;
      double bias = (double)qc_b[d];
#pragma unroll
      for (int r = 0; r < 4; r++) {
        int row = use_alt ? (g + 4 * r) : (4 * g + r);
        int t = t0 + 16 * i + row;
        h64[(size_t)t * 2048 + d] = acc[i][j][r] + bias;
      }
    }
}

// ---------------- fallback proj (proj2b VERIFIED r8-r13) — runs only if self-test tripped ----------------
__global__ __launch_bounds__(256) void k_proj_fb(const float* x32, const float* qc_w, const float* qc_b,
                                                 double* h64, const int* bad) {
  if (*bad == 0) return;
  __shared__ double At[16][128];
  __shared__ double Bt[16][16][9];
  int t0 = blockIdx.y * 128, d0 = blockIdx.x * 128;
  int tid = threadIdx.x;
  int tr = tid >> 4, dc = tid & 15;
  int srow = tid & 127, kh = (tid >> 7) * 8;
  int sg = srow >> 3, se = srow & 7;
  const float* pA = x32 + (size_t)(t0 + srow) * 256 + kh;
  const float* pB = qc_w + (size_t)(d0 + srow) * 256 + kh;
  f32x4 a0 = *(const f32x4*)pA, a1 = *(const f32x4*)(pA + 4);
  f32x4 b0 = *(const f32x4*)pB, b1 = *(const f32x4*)(pB + 4);
  double acc[8][8] = {};
  for (int kk = 0; kk < 256; kk += 16) {
    __syncthreads();
#pragma unroll
    for (int j = 0; j < 4; j++) {
      At[kh + j][srow] = (double)a0[j]; At[kh + 4 + j][srow] = (double)a1[j];
      Bt[kh + j][sg][se] = (double)b0[j]; Bt[kh + 4 + j][sg][se] = (double)b1[j];
    }
    __syncthreads();
    if (kk + 16 < 256) {
      a0 = *(const f32x4*)(pA + kk + 16); a1 = *(const f32x4*)(pA + kk + 20);
      b0 = *(const f32x4*)(pB + kk + 16); b1 = *(const f32x4*)(pB + kk + 20);
    }
#pragma unroll
    for (int k = 0; k < 16; k++) {
      double a[8], b[8];
#pragma unroll
      for (int j = 0; j < 8; j++) a[j] = At[k][tr * 8 + j];
#pragma unroll
      for (int j = 0; j < 8; j++) b[j] = Bt[k][dc][j];
#pragma unroll
      for (int i = 0; i < 8; i++)
#pragma unroll
        for (int j = 0; j < 8; j++)
          acc[i][j] = fma(a[i], b[j], acc[i][j]);
    }
  }
#pragma unroll
  for (int i = 0; i < 8; i++)
#pragma unroll
    for (int j = 0; j < 8; j++) {
      int col = d0 + dc * 8 + j;
      h64[(size_t)(t0 + tr * 8 + i) * 2048 + col] = acc[i][j] + (double)qc_b[col];
    }
}

// ---------------- P' GEMM fused with codebook norms (VERIFIED r7-r16) ----------------
__global__ __launch_bounds__(256) void k_pgemm4(const float* cb, const f16* wT, f16* P16kt,
                                                double* inv64, float* inv32) {
  __shared__ f16 Al[2][64][32];
  __shared__ f16 Bl[2][160][32];
  __shared__ double nsum[64][4];
  __shared__ double invsh[64];
  int j0 = blockIdx.x * 64;
  int c0 = blockIdx.y * 160;
  int tid = threadIdx.x, wid = tid >> 6, lane = tid & 63;
  int cl = lane & 15, g = lane >> 4;
  f32x4 acc[10];
#pragma unroll
  for (int n = 0; n < 10; n++) acc[n] = (f32x4)0.0f;
  int arow = tid & 63, aseg = tid >> 6;
  double s2 = 0.0;

  auto aload = [&](int kk, f32x4& v0, f32x4& v1) {
    v0 = *(const f32x4*)(cb + (size_t)(j0 + arow) * 2048 + kk + aseg * 8);
    v1 = *(const f32x4*)(cb + (size_t)(j0 + arow) * 2048 + kk + aseg * 8 + 4);
  };
  auto addnorm = [&](f32x4 v0, f32x4 v1) {
#pragma unroll
    for (int e = 0; e < 4; e++) {
      s2 += (double)v0[e] * (double)v0[e];
      s2 += (double)v1[e] * (double)v1[e];
    }
  };
  auto awrite = [&](int buf, f32x4 v0, f32x4 v1) {
    f16x8 h;
#pragma unroll
    for (int e = 0; e < 4; e++) { h[e] = (f16)v0[e]; h[4 + e] = (f16)v1[e]; }
    int sp = aseg ^ ((arow >> 1) & 3);
    *(f16x8*)((char*)&Al[buf][arow][0] + sp * 16) = h;
  };
  auto stageB = [&](int kk, int buf) {
#pragma unroll
    for (int i = 0; i < 3; i++) {
      int g2 = wid + 4 * i;
      if (g2 < 10) {
        int r0 = 16 * g2;
        int rl = r0 + (lane >> 2);
        int sl = (lane & 3) ^ ((rl >> 1) & 3);
        gload_lds16(wT + (size_t)(c0 + rl) * 2048 + kk + sl * 8, &Bl[buf][r0][0]);
      }
    }
  };
  auto rdA = [&](int buf, int r, int sg2) -> f16x8 {
    return *(const f16x8*)((const char*)&Al[buf][0][0] + r * 64 + ((sg2 ^ ((r >> 1) & 3)) << 4));
  };
  auto rdB = [&](int buf, int r, int sg2) -> f16x8 {
    return *(const f16x8*)((const char*)&Bl[buf][0][0] + r * 64 + ((sg2 ^ ((r >> 1) & 3)) << 4));
  };

  { f32x4 v0, v1; aload(0, v0, v1); addnorm(v0, v1); awrite(0, v0, v1); }
  stageB(0, 0);
  asm volatile("s_waitcnt vmcnt(0)" ::: "memory");
  __syncthreads();
  for (int s = 0; s < 64; s++) {
    int buf = s & 1;
    f32x4 v0, v1;
    if (s < 63) { aload((s + 1) * 32, v0, v1); stageB((s + 1) * 32, buf ^ 1); }
    f16x8 av = rdA(buf, 16 * wid + cl, g);
#pragma unroll
    for (int n = 0; n < 10; n++) {
      f16x8 bv = rdB(buf, 16 * n + cl, g);
      acc[n] = __builtin_amdgcn_mfma_f32_16x16x32_f16(av, bv, acc[n], 0, 0, 0);
    }
    if (s < 63) { addnorm(v0, v1); awrite(buf ^ 1, v0, v1); }
    asm volatile("s_waitcnt vmcnt(0)" ::: "memory");
    __syncthreads();
  }
  nsum[arow][aseg] = s2;
  __syncthreads();
  if (tid < 64) {
    double t = nsum[tid][0] + nsum[tid][1] + nsum[tid][2] + nsum[tid][3];
    double nn = sqrt(t); nn = fmax(nn, 1e-12);
    double iv = 1.0 / nn;
    invsh[tid] = iv;
    if (blockIdx.y == 0) { inv64[j0 + tid] = iv; inv32[j0 + tid] = (float)iv; }
  }
  __syncthreads();
#pragma unroll
  for (int r = 0; r < 4; r++) {
    int rloc = 16 * wid + 4 * g + r;
    int row = j0 + rloc;
    float sc = (float)invsh[rloc];
#pragma unroll
    for (int n = 0; n < 10; n++) {
      int c = c0 + 16 * n + cl;
      int ks = c >> 5;
      int sl = ((c & 31) >> 3) ^ ((row >> 1) & 3);
      P16kt[(((size_t)ks * KCB + row) << 5) + (sl << 3) + (c & 7)] = (f16)(acc[n][r] * sc);
    }
  }
}

// ---------------- screen v14: 256x256 tile, double buffer (68KB LDS -> 2 blocks/CU), NO reg clamp ----------------
// Grid 1024, XCD swizzle: xcd = bid&7 owns code-blocks [8*xcd, 8*xcd+8).
__global__ __launch_bounds__(512) void k_screen14(const f16* x16, const f16* P16kt,
                                                  int* cnt, float* cand_v, int* cand_i) {
  __shared__ f16 Al[2][256][32];
  __shared__ f16 Bl[2][256][32];
  __shared__ float smx[256][4];
  int bid = blockIdx.x;
  int nb = ((bid & 7) << 3) | ((bid >> 3) & 7);    // code-block 0..63 (256 codes each)
  int tb = bid >> 6;                                // token-block 0..15 (256 tokens each)
  int n0 = nb * 256, t0 = tb * 256;
  int tid = threadIdx.x, wid = tid >> 6, lane = tid & 63;
  int wr = wid >> 2, wc = wid & 3;                  // 2 x 4 wave grid; wave tile 128 x 64
  int cl = lane & 15, g = lane >> 4;
  f32x4 acc[8][4];
#pragma unroll
  for (int m = 0; m < 8; m++)
#pragma unroll
    for (int n = 0; n < 4; n++) acc[m][n] = (f32x4)0.0f;

  auto stageA = [&](int ks, int buf) {
#pragma unroll
    for (int i = 0; i < 2; i++) {
      int r0 = 32 * wid + 16 * i;
      int rl = r0 + (lane >> 2);
      int sl = (lane & 3) ^ ((rl >> 1) & 3);
      gload_lds16(x16 + (size_t)(t0 + rl) * 320 + ks * 32 + sl * 8, &Al[buf][r0][0]);
    }
  };
  auto stageB = [&](int ks, int buf) {
    const f16* src = P16kt + (((size_t)ks * KCB + n0) << 5) + wid * 1024 + lane * 8;
    gload_lds16(src, &Bl[buf][wid * 32][0]);
    gload_lds16(src + 512, &Bl[buf][wid * 32 + 16][0]);
  };
  auto rdA = [&](int buf, int r, int sg) -> f16x8 {
    return *(const f16x8*)((const char*)&Al[buf][0][0] + r * 64 + ((sg ^ ((r >> 1) & 3)) << 4));
  };
  auto rdB = [&](int buf, int r, int sg) -> f16x8 {
    return *(const f16x8*)((const char*)&Bl[buf][0][0] + r * 64 + ((sg ^ ((r >> 1) & 3)) << 4));
  };

  stageA(0, 0); stageB(0, 0);
  __syncthreads();
#pragma unroll
  for (int s = 0; s < 10; s++) {
    const int buf = s & 1;
    if (s < 9) { stageA(s + 1, buf ^ 1); stageB(s + 1, buf ^ 1); }
    f16x8 av[8], bv[4];
#pragma unroll
    for (int m = 0; m < 8; m++) av[m] = rdA(buf, 128 * wr + 16 * m + cl, g);
#pragma unroll
    for (int n = 0; n < 4; n++) bv[n] = rdB(buf, 64 * wc + 16 * n + cl, g);
    __builtin_amdgcn_s_setprio(1);
#pragma unroll
    for (int m = 0; m < 8; m++)
#pragma unroll
      for (int n = 0; n < 4; n++)
        acc[m][n] = __builtin_amdgcn_mfma_f32_16x16x32_f16(av[m], bv[n], acc[m][n], 0, 0, 0);
    __builtin_amdgcn_s_setprio(0);
    __syncthreads();   // drains vmcnt+lgkmcnt; cross-block overlap hides the stall
  }

  // ---- epilogue phase 1: block-local row max (per wave-col partial, then combined)
#pragma unroll
  for (int m = 0; m < 8; m++) {
#pragma unroll
    for (int r = 0; r < 4; r++) {
      float v = -3.4e38f;
#pragma unroll
      for (int n = 0; n < 4; n++) v = fmaxf(v, acc[m][n][r]);
      v = fmaxf(v, __shfl_xor(v, 1));
      v = fmaxf(v, __shfl_xor(v, 2));
      v = fmaxf(v, __shfl_xor(v, 4));
      v = fmaxf(v, __shfl_xor(v, 8));
      if (cl == 0) smx[128 * wr + 16 * m + 4 * g + r][wc] = v;
    }
  }
  __syncthreads();

  // ---- epilogue phase 2: LDS-compacted collection (overlay on dead Al buffer)
  uint32_t* lcnt = (uint32_t*)(&Al[0][0][0]);       // 256 u32
  float*    lval = (float*)(lcnt + 256);            // 256*MAXL f32
  int*      lidx = (int*)(lval + 256 * MAXL);       // 256*MAXL i32
  if (tid < 256) lcnt[tid] = 0;
  __syncthreads();

#pragma unroll
  for (int m = 0; m < 8; m++) {
#pragma unroll
    for (int r = 0; r < 4; r++) {
      int rloc = 128 * wr + 16 * m + 4 * g + r;
      float lim = fmaxf(fmaxf(smx[rloc][0], smx[rloc][1]), fmaxf(smx[rloc][2], smx[rloc][3])) - MARGIN_C;
#pragma unroll
      for (int n = 0; n < 4; n++) {
        float vv = acc[m][n][r];
        if (vv >= lim) {
          uint32_t p = atomicAdd(&lcnt[rloc], 1u);
          int code = n0 + 64 * wc + 16 * n + cl;
          if (p < MAXL) { lval[rloc * MAXL + p] = vv; lidx[rloc * MAXL + p] = code; }
          else {
            int slot = atomicAdd(&cnt[t0 + rloc], 1);
            if (slot < CAP) { cand_v[(t0 + rloc) * CAP + slot] = vv; cand_i[(t0 + rloc) * CAP + slot] = code; }
          }
        }
      }
    }
  }
  __syncthreads();

  // ---- epilogue phase 3: one global atomic per row, bulk copy
  if (tid < 256) {
    int lc = (int)lcnt[tid]; if (lc > MAXL) lc = MAXL;
    if (lc > 0) {
      int row = t0 + tid;
      int base = atomicAdd(&cnt[row], lc);
      for (int i = 0; i < lc; i++) {
        int slot = base + i;
        if (slot < CAP) {
          cand_v[row * CAP + slot] = lval[tid * MAXL + i];
          cand_i[row * CAP + slot] = lidx[tid * MAXL + i];
        }
      }
    }
  }
}

// ---------------- rescore v3: one wave per token, no LDS / no barriers (VERIFIED r14-r16) ----------------
__global__ __launch_bounds__(64) void k_rescore3(const double* h64, const float* cb, const double* inv64,
                                                 const int* cnt, const float* cand_v, const int* cand_i,
                                                 float* idxf, int* idxi) {
  int t = blockIdx.x;
  int lane = threadIdx.x;
  int ctot = cnt[t];
  double bV = -1e300; int bI = 0x7fffffff;
  const double* hrow = h64 + (size_t)t * 2048;
  if (ctot <= CAP) {
    float gm = -3.4e38f;
    for (int c = lane; c < ctot; c += 64) gm = fmaxf(gm, cand_v[t * CAP + c]);
#pragma unroll
    for (int o = 32; o; o >>= 1) gm = fmaxf(gm, __shfl_xor(gm, o));
    float lim = gm - MARGIN_F;
    for (int c = 0; c < ctot; c++) {
      float v = cand_v[t * CAP + c];
      if (v < lim) continue;
      int code = cand_i[t * CAP + c];
      const float* crow = cb + (size_t)code * 2048;
      double p = 0.0;
#pragma unroll
      for (int e = 0; e < 32; e++) {
        int d = lane + 64 * e;
        p = fma(hrow[d], (double)crow[d], p);
      }
#pragma unroll
      for (int o = 32; o; o >>= 1) p += __shfl_xor(p, o);
      double sv = p * inv64[code];
      if (sv > bV || (sv == bV && code < bI)) { bV = sv; bI = code; }
    }
  } else {
    for (int code = 0; code < KCB; code++) {
      const float* crow = cb + (size_t)code * 2048;
      double p = 0.0;
      for (int e = 0; e < 32; e++) {
        int d = lane + 64 * e;
        p = fma(hrow[d], (double)crow[d], p);
      }
      for (int o = 32; o; o >>= 1) p += __shfl_xor(p, o);
      double sv = p * inv64[code];
      if (sv > bV || (sv == bV && code < bI)) { bV = sv; bI = code; }
    }
  }
  if (lane == 0) { idxi[t] = bI; idxf[t] = (float)bI; }
}

// ---------------- gather quant output ----------------
__global__ __launch_bounds__(256) void k_quant(const float* cb, const float* inv32, const int* idxi, float* out0) {
  int hw = blockIdx.x * 256 + threadIdx.x;
  int d = blockIdx.y, b = blockIdx.z;
  int t = b * 1024 + hw;
  int row = idxi[t];
  out0[((size_t)b * 2048 + d) * 1024 + hw] = cb[(size_t)row * 2048 + d] * inv32[row];
}

extern "C" void kernel_launch(void* const* d_in, const int* in_sizes, int n_in,
                              void* d_out, int out_size, void* d_ws, size_t ws_size,
                              hipStream_t stream) {
  const float* hid = (const float*)d_in[0];
  const float* cb  = (const float*)d_in[1];
  const float* qw  = (const float*)d_in[2];
  const float* qb  = (const float*)d_in[3];
  float* out = (float*)d_out;  // [4*2048*1024 quant][4096 idx-as-float]

  char* w = (char*)d_ws;
  size_t off = 0;
  auto alloc = [&](size_t bytes) -> void* {
    void* p = w + off;
    off += (bytes + 255) & ~(size_t)255;
    return p;
  };
  double* h64   = (double*)alloc((size_t)NTOK * 2048 * 8);
  f16*    x16   = (f16*)   alloc((size_t)NTOK * 320 * 2);
  float*  x32   = (float*) alloc((size_t)NTOK * 256 * 4);
  f16*    wT    = (f16*)   alloc((size_t)320 * 2048 * 2);
  f16*    P16kt = (f16*)   alloc((size_t)10 * KCB * 32 * 2);
  double* inv64 = (double*)alloc((size_t)KCB * 8);
  float*  inv32 = (float*) alloc((size_t)KCB * 4);
  int*    cnt   = (int*)   alloc((size_t)NTOK * 4);
  float*  cand_v= (float*) alloc((size_t)NTOK * CAP * 4);
  int*    cand_i= (int*)   alloc((size_t)NTOK * CAP * 4);
  int*    idxi  = (int*)   alloc((size_t)NTOK * 4);
  int*    bad   = (int*)   alloc(256);

  k_init<<<16, 256, 0, stream>>>(cnt, bad);
  k_build_wT<<<dim3(32, 5), 256, 0, stream>>>(qw, qb, wT);
  k_build_x<<<dim3(16, 4, 4), 256, 0, stream>>>(hid, x16, x32);
  k_proj_mfma<<<dim3(16, 64), 256, 0, stream>>>(x32, qw, qb, h64, bad);
  k_proj_fb<<<dim3(16, 32), 256, 0, stream>>>(x32, qw, qb, h64, bad);
  k_pgemm4<<<dim3(256, 2), 256, 0, stream>>>(cb, wT, P16kt, inv64, inv32);
  k_screen14<<<1024, 512, 0, stream>>>(x16, P16kt, cnt, cand_v, cand_i);
  k_rescore3<<<NTOK, 64, 0, stream>>>(h64, cb, inv64, cnt, cand_v, cand_i, out + 8388608, idxi);
  k_quant<<<dim3(4, 2048, 4), 256, 0, stream>>>(cb, inv32, idxi, out);
}

// Round 19
// 355.793 us; speedup vs baseline: 2.0422x; 1.0100x over previous
//
#include <hip/hip_runtime.h>
#include <hip/hip_fp16.h>
#include <stdint.h>

#define NTOK 4096
#define KCB  16384
#define CAP  256
#define MAXL 8           // per-row per-block LDS compaction slots
#define MARGIN_C 0.02f   // collection margin (~15x worst-case f16 screen error)
#define MARGIN_F 0.02f   // filter margin in rescore

typedef _Float16 f16;
typedef _Float16 f16x8 __attribute__((ext_vector_type(8)));
typedef float f32x4 __attribute__((ext_vector_type(4)));
typedef double f64x4 __attribute__((ext_vector_type(4)));

typedef const __attribute__((address_space(1))) uint32_t* gptr_t;
typedef __attribute__((address_space(3))) uint32_t* lptr_t;
__device__ __forceinline__ void gload_lds16(const void* g, void* l) {
  __builtin_amdgcn_global_load_lds((gptr_t)g, (lptr_t)l, 16, 0, 0);
}

// ---------------- init ----------------
__global__ void k_init(int* cnt, int* bad) {
  int i = blockIdx.x * 256 + threadIdx.x;
  if (i < NTOK) cnt[i] = 0;
  if (blockIdx.x == 0 && threadIdx.x == 0) *bad = 0;
}

// ---------------- build W~^T (320 x 2048) f16 ----------------
__global__ __launch_bounds__(256) void k_build_wT(const float* qc_w, const float* qc_b, f16* wT) {
  __shared__ float tl[64][65];
  int d0 = blockIdx.x * 64, c0 = blockIdx.y * 64;
  int jj = threadIdx.x & 63, i0 = threadIdx.x >> 6;
  for (int ii = 0; ii < 64; ii += 4) {
    int i = ii + i0; int d = d0 + i; int c = c0 + jj;
    float v = 0.f;
    if (c < 256) v = qc_w[(size_t)d * 256 + c];
    else if (c == 256) v = qc_b[d];
    tl[i][jj] = v;
  }
  __syncthreads();
  for (int jj2 = 0; jj2 < 64; jj2 += 4) {
    int j = jj2 + i0; int i = threadIdx.x & 63;
    wT[(size_t)(c0 + j) * 2048 + d0 + i] = (f16)tl[i][j];
  }
}

// ---------------- build x tokens ----------------
__global__ __launch_bounds__(256) void k_build_x(const float* hid, f16* x16, float* x32) {
  __shared__ float tl[64][65];
  int hw0 = blockIdx.x * 64, c0 = blockIdx.y * 64, b = blockIdx.z;
  int jj = threadIdx.x & 63, i0 = threadIdx.x >> 6;
  for (int ii = 0; ii < 64; ii += 4) {
    int i = ii + i0;
    tl[i][jj] = hid[((size_t)b * 256 + c0 + i) * 1024 + hw0 + jj];
  }
  __syncthreads();
  for (int jj2 = 0; jj2 < 64; jj2 += 4) {
    int j = jj2 + i0; int i = threadIdx.x & 63;
    int t = b * 1024 + hw0 + j; float v = tl[i][j];
    x32[(size_t)t * 256 + c0 + i] = v;
    x16[(size_t)t * 320 + c0 + i] = (f16)v;
  }
  if (blockIdx.y == 0) {
    int tb = b * 1024 + hw0;
    for (int q = 0; q < 16; q++) {
      int idx2 = threadIdx.x * 16 + q;
      int tl2 = idx2 >> 6, p = idx2 & 63;
      x16[(size_t)(tb + tl2) * 320 + 256 + p] = (p == 0) ? (f16)1.0f : (f16)0.0f;
    }
  }
}

// ---------------- fallback proj (proj2b VERIFIED r8-r13) — runs only if self-test tripped ----------------
__global__ __launch_bounds__(256) void k_proj_fb(const float* x32, const float* qc_w, const float* qc_b,
                                                 double* h64, const int* bad) {
  if (*bad == 0) return;
  __shared__ double At[16][128];
  __shared__ double Bt[16][16][9];
  int t0 = blockIdx.y * 128, d0 = blockIdx.x * 128;
  int tid = threadIdx.x;
  int tr = tid >> 4, dc = tid & 15;
  int srow = tid & 127, kh = (tid >> 7) * 8;
  int sg = srow >> 3, se = srow & 7;
  const float* pA = x32 + (size_t)(t0 + srow) * 256 + kh;
  const float* pB = qc_w + (size_t)(d0 + srow) * 256 + kh;
  f32x4 a0 = *(const f32x4*)pA, a1 = *(const f32x4*)(pA + 4);
  f32x4 b0 = *(const f32x4*)pB, b1 = *(const f32x4*)(pB + 4);
  double acc[8][8] = {};
  for (int kk = 0; kk < 256; kk += 16) {
    __syncthreads();
#pragma unroll
    for (int j = 0; j < 4; j++) {
      At[kh + j][srow] = (double)a0[j]; At[kh + 4 + j][srow] = (double)a1[j];
      Bt[kh + j][sg][se] = (double)b0[j]; Bt[kh + 4 + j][sg][se] = (double)b1[j];
    }
    __syncthreads();
    if (kk + 16 < 256) {
      a0 = *(const f32x4*)(pA + kk + 16); a1 = *(const f32x4*)(pA + kk + 20);
      b0 = *(const f32x4*)(pB + kk + 16); b1 = *(const f32x4*)(pB + kk + 20);
    }
#pragma unroll
    for (int k = 0; k < 16; k++) {
      double a[8], b[8];
#pragma unroll
      for (int j = 0; j < 8; j++) a[j] = At[k][tr * 8 + j];
#pragma unroll
      for (int j = 0; j < 8; j++) b[j] = Bt[k][dc][j];
#pragma unroll
      for (int i = 0; i < 8; i++)
#pragma unroll
        for (int j = 0; j < 8; j++)
          acc[i][j] = fma(a[i], b[j], acc[i][j]);
    }
  }
#pragma unroll
  for (int i = 0; i < 8; i++)
#pragma unroll
    for (int j = 0; j < 8; j++) {
      int col = d0 + dc * 8 + j;
      h64[(size_t)(t0 + tr * 8 + i) * 2048 + col] = acc[i][j] + (double)qc_b[col];
    }
}

// ---------------- P' GEMM fused with codebook norms (VERIFIED r7-r18) ----------------
__global__ __launch_bounds__(256) void k_pgemm4(const float* cb, const f16* wT, f16* P16kt,
                                                double* inv64, float* inv32) {
  __shared__ f16 Al[2][64][32];
  __shared__ f16 Bl[2][160][32];
  __shared__ double nsum[64][4];
  __shared__ double invsh[64];
  int j0 = blockIdx.x * 64;
  int c0 = blockIdx.y * 160;
  int tid = threadIdx.x, wid = tid >> 6, lane = tid & 63;
  int cl = lane & 15, g = lane >> 4;
  f32x4 acc[10];
#pragma unroll
  for (int n = 0; n < 10; n++) acc[n] = (f32x4)0.0f;
  int arow = tid & 63, aseg = tid >> 6;
  double s2 = 0.0;

  auto aload = [&](int kk, f32x4& v0, f32x4& v1) {
    v0 = *(const f32x4*)(cb + (size_t)(j0 + arow) * 2048 + kk + aseg * 8);
    v1 = *(const f32x4*)(cb + (size_t)(j0 + arow) * 2048 + kk + aseg * 8 + 4);
  };
  auto addnorm = [&](f32x4 v0, f32x4 v1) {
#pragma unroll
    for (int e = 0; e < 4; e++) {
      s2 += (double)v0[e] * (double)v0[e];
      s2 += (double)v1[e] * (double)v1[e];
    }
  };
  auto awrite = [&](int buf, f32x4 v0, f32x4 v1) {
    f16x8 h;
#pragma unroll
    for (int e = 0; e < 4; e++) { h[e] = (f16)v0[e]; h[4 + e] = (f16)v1[e]; }
    int sp = aseg ^ ((arow >> 1) & 3);
    *(f16x8*)((char*)&Al[buf][arow][0] + sp * 16) = h;
  };
  auto stageB = [&](int kk, int buf) {
#pragma unroll
    for (int i = 0; i < 3; i++) {
      int g2 = wid + 4 * i;
      if (g2 < 10) {
        int r0 = 16 * g2;
        int rl = r0 + (lane >> 2);
        int sl = (lane & 3) ^ ((rl >> 1) & 3);
        gload_lds16(wT + (size_t)(c0 + rl) * 2048 + kk + sl * 8, &Bl[buf][r0][0]);
      }
    }
  };
  auto rdA = [&](int buf, int r, int sg2) -> f16x8 {
    return *(const f16x8*)((const char*)&Al[buf][0][0] + r * 64 + ((sg2 ^ ((r >> 1) & 3)) << 4));
  };
  auto rdB = [&](int buf, int r, int sg2) -> f16x8 {
    return *(const f16x8*)((const char*)&Bl[buf][0][0] + r * 64 + ((sg2 ^ ((r >> 1) & 3)) << 4));
  };

  { f32x4 v0, v1; aload(0, v0, v1); addnorm(v0, v1); awrite(0, v0, v1); }
  stageB(0, 0);
  asm volatile("s_waitcnt vmcnt(0)" ::: "memory");
  __syncthreads();
  for (int s = 0; s < 64; s++) {
    int buf = s & 1;
    f32x4 v0, v1;
    if (s < 63) { aload((s + 1) * 32, v0, v1); stageB((s + 1) * 32, buf ^ 1); }
    f16x8 av = rdA(buf, 16 * wid + cl, g);
#pragma unroll
    for (int n = 0; n < 10; n++) {
      f16x8 bv = rdB(buf, 16 * n + cl, g);
      acc[n] = __builtin_amdgcn_mfma_f32_16x16x32_f16(av, bv, acc[n], 0, 0, 0);
    }
    if (s < 63) { addnorm(v0, v1); awrite(buf ^ 1, v0, v1); }
    asm volatile("s_waitcnt vmcnt(0)" ::: "memory");
    __syncthreads();
  }
  nsum[arow][aseg] = s2;
  __syncthreads();
  if (tid < 64) {
    double t = nsum[tid][0] + nsum[tid][1] + nsum[tid][2] + nsum[tid][3];
    double nn = sqrt(t); nn = fmax(nn, 1e-12);
    double iv = 1.0 / nn;
    invsh[tid] = iv;
    if (blockIdx.y == 0) { inv64[j0 + tid] = iv; inv32[j0 + tid] = (float)iv; }
  }
  __syncthreads();
#pragma unroll
  for (int r = 0; r < 4; r++) {
    int rloc = 16 * wid + 4 * g + r;
    int row = j0 + rloc;
    float sc = (float)invsh[rloc];
#pragma unroll
    for (int n = 0; n < 10; n++) {
      int c = c0 + 16 * n + cl;
      int ks = c >> 5;
      int sl = ((c & 31) >> 3) ^ ((row >> 1) & 3);
      P16kt[(((size_t)ks * KCB + row) << 5) + (sl << 3) + (c & 7)] = (f16)(acc[n][r] * sc);
    }
  }
}

// ---------------- FUSED kernel: screen blocks (bid%3 != 2) + proj blocks (bid%3 == 2) ----------------
// Screen: 256x256 tile, double-buffer (r18-verified structure). Proj: f64 MFMA, 128t x 128d per block,
// two 64-token halves sharing one B tile. LDS union 69632 B -> 2 blocks/CU.
__global__ __launch_bounds__(512) void k_fused(const f16* x16, const f16* P16kt,
                                               const float* x32, const float* qc_w, const float* qc_b,
                                               double* h64, int* bad,
                                               int* cnt, float* cand_v, int* cand_i) {
  __shared__ __align__(16) char smem[69632];
  int bid = blockIdx.x;
  int tid = threadIdx.x, lane = tid & 63;
  int cl = lane & 15, g = lane >> 4;
  int rr3 = bid % 3;

  if (rr3 == 2) {
    // ================= PROJ PATH =================
    int pb = bid / 3;                      // 0..511
    int d0 = (pb & 15) * 128, t0 = (pb >> 4) * 128;
    int half = tid >> 8, htid = tid & 255;
    int hwid = htid >> 6;                  // 0..3
    int t0h = t0 + half * 64;

    // layout self-test (r14-verified)
    double ta1 = (double)cl;
    double tb1 = (g == 0) ? 1.0 : 0.0;
    f64x4 tc1 = {0.0, 0.0, 0.0, 0.0};
    tc1 = __builtin_amdgcn_mfma_f64_16x16x4f64(ta1, tb1, tc1, 0, 0, 0);
    double ta2 = (g == 0) ? 1.0 : 0.0;
    double tb2 = (g == 0) ? (double)cl : 0.0;
    f64x4 tc2 = {0.0, 0.0, 0.0, 0.0};
    tc2 = __builtin_amdgcn_mfma_f64_16x16x4f64(ta2, tb2, tc2, 0, 0, 0);
    bool std_ok = true, alt_ok = true, col_ok = true;
#pragma unroll
    for (int r = 0; r < 4; r++) {
      std_ok = std_ok && (tc1[r] == (double)(4 * g + r));
      alt_ok = alt_ok && (tc1[r] == (double)(g + 4 * r));
      col_ok = col_ok && (tc2[r] == (double)cl);
    }
    unsigned long long mstd = __ballot(std_ok), malt = __ballot(alt_ok), mcol = __ballot(col_ok);
    bool all_std = (mstd == ~0ull), all_alt = (malt == ~0ull), all_col = (mcol == ~0ull);
    bool good = (all_std || all_alt) && all_col;
    if (!good) { if (tid == 0) atomicOr(bad, 1); return; }
    int use_alt = all_alt ? 1 : 0;

    // LDS: At[2][32][66] doubles (33792 B) then Bt[32][130] doubles (33280 B)
    double (*At)[32][66] = (double(*)[32][66])smem;
    double (*Bt)[130] = (double(*)[130])(smem + 33792);

    int t_a = htid & 63, ka = (htid >> 6) * 8;   // per-half A staging: 8 f32 each
    int d_b = tid & 127, kb = (tid >> 7) * 8;    // shared B staging: 8 f32 each
    f32x4 ra0, ra1, rb0, rb1;
    auto ldregs = [&](int kc) {
      ra0 = *(const f32x4*)(x32 + (size_t)(t0h + t_a) * 256 + kc + ka);
      ra1 = *(const f32x4*)(x32 + (size_t)(t0h + t_a) * 256 + kc + ka + 4);
      rb0 = *(const f32x4*)(qc_w + (size_t)(d0 + d_b) * 256 + kc + kb);
      rb1 = *(const f32x4*)(qc_w + (size_t)(d0 + d_b) * 256 + kc + kb + 4);
    };
    ldregs(0);

    f64x4 acc[4][2];
#pragma unroll
    for (int i = 0; i < 4; i++)
#pragma unroll
      for (int j = 0; j < 2; j++) acc[i][j] = (f64x4)0.0;

    for (int c = 0; c < 8; c++) {
      __syncthreads();
#pragma unroll
      for (int e = 0; e < 4; e++) {
        At[half][ka + e][t_a] = (double)ra0[e];
        At[half][ka + 4 + e][t_a] = (double)ra1[e];
        Bt[kb + e][d_b] = (double)rb0[e];
        Bt[kb + 4 + e][d_b] = (double)rb1[e];
      }
      __syncthreads();
      if (c < 7) ldregs((c + 1) * 32);
#pragma unroll
      for (int k4 = 0; k4 < 8; k4++) {
        int k = k4 * 4 + g;
        double a[4], b[2];
#pragma unroll
        for (int i = 0; i < 4; i++) a[i] = At[half][k][16 * i + cl];
#pragma unroll
        for (int j = 0; j < 2; j++) b[j] = Bt[k][32 * hwid + 16 * j + cl];
#pragma unroll
        for (int i = 0; i < 4; i++)
#pragma unroll
          for (int j = 0; j < 2; j++)
            acc[i][j] = __builtin_amdgcn_mfma_f64_16x16x4f64(a[i], b[j], acc[i][j], 0, 0, 0);
      }
    }
#pragma unroll
    for (int i = 0; i < 4; i++)
#pragma unroll
      for (int j = 0; j < 2; j++) {
        int d = d0 + 32 * hwid + 16 * j + cl;
        double bias = (double)qc_b[d];
#pragma unroll
        for (int r = 0; r < 4; r++) {
          int row = use_alt ? (g + 4 * r) : (4 * g + r);
          int t = t0h + 16 * i + row;
          h64[(size_t)t * 2048 + d] = acc[i][j][r] + bias;
        }
      }
    return;
  }

  // ================= SCREEN PATH (r18-verified structure) =================
  int sb = (bid / 3) * 2 + rr3;            // 0..1023
  f16 (*Al)[256][32] = (f16(*)[256][32])smem;                 // 2 x 16384 B
  f16 (*Bl)[256][32] = (f16(*)[256][32])(smem + 32768);       // 2 x 16384 B
  float (*smx)[4] = (float(*)[4])(smem + 65536);              // 4096 B
  int nb = ((sb & 7) << 3) | ((sb >> 3) & 7);
  int tb = sb >> 6;
  int n0 = nb * 256, t0 = tb * 256;
  int wid = tid >> 6;
  int wr = wid >> 2, wc = wid & 3;
  f32x4 acc[8][4];
#pragma unroll
  for (int m = 0; m < 8; m++)
#pragma unroll
    for (int n = 0; n < 4; n++) acc[m][n] = (f32x4)0.0f;

  auto stageA = [&](int ks, int buf) {
#pragma unroll
    for (int i = 0; i < 2; i++) {
      int r0 = 32 * wid + 16 * i;
      int rl = r0 + (lane >> 2);
      int sl = (lane & 3) ^ ((rl >> 1) & 3);
      gload_lds16(x16 + (size_t)(t0 + rl) * 320 + ks * 32 + sl * 8, &Al[buf][r0][0]);
    }
  };
  auto stageB = [&](int ks, int buf) {
    const f16* src = P16kt + (((size_t)ks * KCB + n0) << 5) + wid * 1024 + lane * 8;
    gload_lds16(src, &Bl[buf][wid * 32][0]);
    gload_lds16(src + 512, &Bl[buf][wid * 32 + 16][0]);
  };
  auto rdA = [&](int buf, int r, int sg) -> f16x8 {
    return *(const f16x8*)((const char*)&Al[buf][0][0] + r * 64 + ((sg ^ ((r >> 1) & 3)) << 4));
  };
  auto rdB = [&](int buf, int r, int sg) -> f16x8 {
    return *(const f16x8*)((const char*)&Bl[buf][0][0] + r * 64 + ((sg ^ ((r >> 1) & 3)) << 4));
  };

  stageA(0, 0); stageB(0, 0);
  __syncthreads();
#pragma unroll
  for (int s = 0; s < 10; s++) {
    const int buf = s & 1;
    if (s < 9) { stageA(s + 1, buf ^ 1); stageB(s + 1, buf ^ 1); }
    f16x8 av[8], bv[4];
#pragma unroll
    for (int m = 0; m < 8; m++) av[m] = rdA(buf, 128 * wr + 16 * m + cl, g);
#pragma unroll
    for (int n = 0; n < 4; n++) bv[n] = rdB(buf, 64 * wc + 16 * n + cl, g);
    __builtin_amdgcn_s_setprio(1);
#pragma unroll
    for (int m = 0; m < 8; m++)
#pragma unroll
      for (int n = 0; n < 4; n++)
        acc[m][n] = __builtin_amdgcn_mfma_f32_16x16x32_f16(av[m], bv[n], acc[m][n], 0, 0, 0);
    __builtin_amdgcn_s_setprio(0);
    __syncthreads();
  }

#pragma unroll
  for (int m = 0; m < 8; m++) {
#pragma unroll
    for (int r = 0; r < 4; r++) {
      float v = -3.4e38f;
#pragma unroll
      for (int n = 0; n < 4; n++) v = fmaxf(v, acc[m][n][r]);
      v = fmaxf(v, __shfl_xor(v, 1));
      v = fmaxf(v, __shfl_xor(v, 2));
      v = fmaxf(v, __shfl_xor(v, 4));
      v = fmaxf(v, __shfl_xor(v, 8));
      if (cl == 0) smx[128 * wr + 16 * m + 4 * g + r][wc] = v;
    }
  }
  __syncthreads();

  uint32_t* lcnt = (uint32_t*)smem;
  float*    lval = (float*)(lcnt + 256);
  int*      lidx = (int*)(lval + 256 * MAXL);
  if (tid < 256) lcnt[tid] = 0;
  __syncthreads();

#pragma unroll
  for (int m = 0; m < 8; m++) {
#pragma unroll
    for (int r = 0; r < 4; r++) {
      int rloc = 128 * wr + 16 * m + 4 * g + r;
      float lim = fmaxf(fmaxf(smx[rloc][0], smx[rloc][1]), fmaxf(smx[rloc][2], smx[rloc][3])) - MARGIN_C;
#pragma unroll
      for (int n = 0; n < 4; n++) {
        float vv = acc[m][n][r];
        if (vv >= lim) {
          uint32_t p = atomicAdd(&lcnt[rloc], 1u);
          int code = n0 + 64 * wc + 16 * n + cl;
          if (p < MAXL) { lval[rloc * MAXL + p] = vv; lidx[rloc * MAXL + p] = code; }
          else {
            int slot = atomicAdd(&cnt[t0 + rloc], 1);
            if (slot < CAP) { cand_v[(t0 + rloc) * CAP + slot] = vv; cand_i[(t0 + rloc) * CAP + slot] = code; }
          }
        }
      }
    }
  }
  __syncthreads();

  if (tid < 256) {
    int lc = (int)lcnt[tid]; if (lc > MAXL) lc = MAXL;
    if (lc > 0) {
      int row = t0 + tid;
      int base = atomicAdd(&cnt[row], lc);
      for (int i = 0; i < lc; i++) {
        int slot = base + i;
        if (slot < CAP) {
          cand_v[row * CAP + slot] = lval[tid * MAXL + i];
          cand_i[row * CAP + slot] = lidx[tid * MAXL + i];
        }
      }
    }
  }
}

// ---------------- rescore v3: one wave per token (VERIFIED r14-r18) ----------------
__global__ __launch_bounds__(64) void k_rescore3(const double* h64, const float* cb, const double* inv64,
                                                 const int* cnt, const float* cand_v, const int* cand_i,
                                                 float* idxf, int* idxi) {
  int t = blockIdx.x;
  int lane = threadIdx.x;
  int ctot = cnt[t];
  double bV = -1e300; int bI = 0x7fffffff;
  const double* hrow = h64 + (size_t)t * 2048;
  if (ctot <= CAP) {
    float gm = -3.4e38f;
    for (int c = lane; c < ctot; c += 64) gm = fmaxf(gm, cand_v[t * CAP + c]);
#pragma unroll
    for (int o = 32; o; o >>= 1) gm = fmaxf(gm, __shfl_xor(gm, o));
    float lim = gm - MARGIN_F;
    for (int c = 0; c < ctot; c++) {
      float v = cand_v[t * CAP + c];
      if (v < lim) continue;
      int code = cand_i[t * CAP + c];
      const float* crow = cb + (size_t)code * 2048;
      double p = 0.0;
#pragma unroll
      for (int e = 0; e < 32; e++) {
        int d = lane + 64 * e;
        p = fma(hrow[d], (double)crow[d], p);
      }
#pragma unroll
      for (int o = 32; o; o >>= 1) p += __shfl_xor(p, o);
      double sv = p * inv64[code];
      if (sv > bV || (sv == bV && code < bI)) { bV = sv; bI = code; }
    }
  } else {
    for (int code = 0; code < KCB; code++) {
      const float* crow = cb + (size_t)code * 2048;
      double p = 0.0;
      for (int e = 0; e < 32; e++) {
        int d = lane + 64 * e;
        p = fma(hrow[d], (double)crow[d], p);
      }
      for (int o = 32; o; o >>= 1) p += __shfl_xor(p, o);
      double sv = p * inv64[code];
      if (sv > bV || (sv == bV && code < bI)) { bV = sv; bI = code; }
    }
  }
  if (lane == 0) { idxi[t] = bI; idxf[t] = (float)bI; }
}

// ---------------- gather quant output ----------------
__global__ __launch_bounds__(256) void k_quant(const float* cb, const float* inv32, const int* idxi, float* out0) {
  int hw = blockIdx.x * 256 + threadIdx.x;
  int d = blockIdx.y, b = blockIdx.z;
  int t = b * 1024 + hw;
  int row = idxi[t];
  out0[((size_t)b * 2048 + d) * 1024 + hw] = cb[(size_t)row * 2048 + d] * inv32[row];
}

extern "C" void kernel_launch(void* const* d_in, const int* in_sizes, int n_in,
                              void* d_out, int out_size, void* d_ws, size_t ws_size,
                              hipStream_t stream) {
  const float* hid = (const float*)d_in[0];
  const float* cb  = (const float*)d_in[1];
  const float* qw  = (const float*)d_in[2];
  const float* qb  = (const float*)d_in[3];
  float* out = (float*)d_out;  // [4*2048*1024 quant][4096 idx-as-float]

  char* w = (char*)d_ws;
  size_t off = 0;
  auto alloc = [&](size_t bytes) -> void* {
    void* p = w + off;
    off += (bytes + 255) & ~(size_t)255;
    return p;
  };
  double* h64   = (double*)alloc((size_t)NTOK * 2048 * 8);
  f16*    x16   = (f16*)   alloc((size_t)NTOK * 320 * 2);
  float*  x32   = (float*) alloc((size_t)NTOK * 256 * 4);
  f16*    wT    = (f16*)   alloc((size_t)320 * 2048 * 2);
  f16*    P16kt = (f16*)   alloc((size_t)10 * KCB * 32 * 2);
  double* inv64 = (double*)alloc((size_t)KCB * 8);
  float*  inv32 = (float*) alloc((size_t)KCB * 4);
  int*    cnt   = (int*)   alloc((size_t)NTOK * 4);
  float*  cand_v= (float*) alloc((size_t)NTOK * CAP * 4);
  int*    cand_i= (int*)   alloc((size_t)NTOK * CAP * 4);
  int*    idxi  = (int*)   alloc((size_t)NTOK * 4);
  int*    bad   = (int*)   alloc(256);

  k_init<<<16, 256, 0, stream>>>(cnt, bad);
  k_build_wT<<<dim3(32, 5), 256, 0, stream>>>(qw, qb, wT);
  k_build_x<<<dim3(16, 4, 4), 256, 0, stream>>>(hid, x16, x32);
  k_pgemm4<<<dim3(256, 2), 256, 0, stream>>>(cb, wT, P16kt, inv64, inv32);
  k_fused<<<1536, 512, 0, stream>>>(x16, P16kt, x32, qw, qb, h64, bad, cnt, cand_v, cand_i);
  k_proj_fb<<<dim3(16, 32), 256, 0, stream>>>(x32, qw, qb, h64, bad);
  k_rescore3<<<NTOK, 64, 0, stream>>>(h64, cb, inv64, cnt, cand_v, cand_i, out + 8388608, idxi);
  k_quant<<<dim3(4, 2048, 4), 256, 0, stream>>>(cb, inv32, idxi, out);
}

// Round 20
// 341.741 us; speedup vs baseline: 2.1262x; 1.0411x over previous
//
#include <hip/hip_runtime.h>
#include <hip/hip_fp16.h>
#include <stdint.h>

#define NTOK 4096
#define KCB  16384
#define CAP  256
#define MAXL 8           // per-row per-block LDS compaction slots
#define MARGIN_C 0.02f   // collection margin (~15x worst-case f16 screen error)
#define MARGIN_F 0.02f   // filter margin in rescore

typedef _Float16 f16;
typedef _Float16 f16x8 __attribute__((ext_vector_type(8)));
typedef float f32x4 __attribute__((ext_vector_type(4)));
typedef double f64x4 __attribute__((ext_vector_type(4)));

typedef const __attribute__((address_space(1))) uint32_t* gptr_t;
typedef __attribute__((address_space(3))) uint32_t* lptr_t;
__device__ __forceinline__ void gload_lds16(const void* g, void* l) {
  __builtin_amdgcn_global_load_lds((gptr_t)g, (lptr_t)l, 16, 0, 0);
}

// ---------------- init ----------------
__global__ void k_init(int* cnt, int* bad) {
  int i = blockIdx.x * 256 + threadIdx.x;
  if (i < NTOK) cnt[i] = 0;
  if (blockIdx.x == 0 && threadIdx.x == 0) *bad = 0;
}

// ---------------- build W~^T (320 x 2048) f16 ----------------
__global__ __launch_bounds__(256) void k_build_wT(const float* qc_w, const float* qc_b, f16* wT) {
  __shared__ float tl[64][65];
  int d0 = blockIdx.x * 64, c0 = blockIdx.y * 64;
  int jj = threadIdx.x & 63, i0 = threadIdx.x >> 6;
  for (int ii = 0; ii < 64; ii += 4) {
    int i = ii + i0; int d = d0 + i; int c = c0 + jj;
    float v = 0.f;
    if (c < 256) v = qc_w[(size_t)d * 256 + c];
    else if (c == 256) v = qc_b[d];
    tl[i][jj] = v;
  }
  __syncthreads();
  for (int jj2 = 0; jj2 < 64; jj2 += 4) {
    int j = jj2 + i0; int i = threadIdx.x & 63;
    wT[(size_t)(c0 + j) * 2048 + d0 + i] = (f16)tl[i][j];
  }
}

// ---------------- build x tokens ----------------
__global__ __launch_bounds__(256) void k_build_x(const float* hid, f16* x16, float* x32) {
  __shared__ float tl[64][65];
  int hw0 = blockIdx.x * 64, c0 = blockIdx.y * 64, b = blockIdx.z;
  int jj = threadIdx.x & 63, i0 = threadIdx.x >> 6;
  for (int ii = 0; ii < 64; ii += 4) {
    int i = ii + i0;
    tl[i][jj] = hid[((size_t)b * 256 + c0 + i) * 1024 + hw0 + jj];
  }
  __syncthreads();
  for (int jj2 = 0; jj2 < 64; jj2 += 4) {
    int j = jj2 + i0; int i = threadIdx.x & 63;
    int t = b * 1024 + hw0 + j; float v = tl[i][j];
    x32[(size_t)t * 256 + c0 + i] = v;
    x16[(size_t)t * 320 + c0 + i] = (f16)v;
  }
  if (blockIdx.y == 0) {
    int tb = b * 1024 + hw0;
    for (int q = 0; q < 16; q++) {
      int idx2 = threadIdx.x * 16 + q;
      int tl2 = idx2 >> 6, p = idx2 & 63;
      x16[(size_t)(tb + tl2) * 320 + 256 + p] = (p == 0) ? (f16)1.0f : (f16)0.0f;
    }
  }
}

// ---------------- proj via f64 MFMA with runtime layout self-test (VERIFIED r14/r15) ----------------
__global__ __launch_bounds__(256) void k_proj_mfma(const float* x32, const float* qc_w, const float* qc_b,
                                                   double* h64, int* bad) {
  __shared__ double At[32][66];
  __shared__ double Bt[32][130];
  int d0 = blockIdx.x * 128, t0 = blockIdx.y * 64;
  int tid = threadIdx.x, wid = tid >> 6, lane = tid & 63;
  int cl = lane & 15, g = lane >> 4;

  double ta1 = (double)cl;
  double tb1 = (g == 0) ? 1.0 : 0.0;
  f64x4 tc1 = {0.0, 0.0, 0.0, 0.0};
  tc1 = __builtin_amdgcn_mfma_f64_16x16x4f64(ta1, tb1, tc1, 0, 0, 0);
  double ta2 = (g == 0) ? 1.0 : 0.0;
  double tb2 = (g == 0) ? (double)cl : 0.0;
  f64x4 tc2 = {0.0, 0.0, 0.0, 0.0};
  tc2 = __builtin_amdgcn_mfma_f64_16x16x4f64(ta2, tb2, tc2, 0, 0, 0);
  bool std_ok = true, alt_ok = true, col_ok = true;
#pragma unroll
  for (int r = 0; r < 4; r++) {
    std_ok = std_ok && (tc1[r] == (double)(4 * g + r));
    alt_ok = alt_ok && (tc1[r] == (double)(g + 4 * r));
    col_ok = col_ok && (tc2[r] == (double)cl);
  }
  unsigned long long mstd = __ballot(std_ok), malt = __ballot(alt_ok), mcol = __ballot(col_ok);
  bool all_std = (mstd == ~0ull), all_alt = (malt == ~0ull), all_col = (mcol == ~0ull);
  bool good = (all_std || all_alt) && all_col;
  if (!good) { if (tid == 0) atomicOr(bad, 1); return; }
  int use_alt = all_alt ? 1 : 0;

  int t_a = tid & 63, ka = (tid >> 6) * 8;
  int d_b = tid & 127, kb = (tid >> 7) * 16;
  f32x4 ra0, ra1, rb0, rb1, rb2, rb3;
  auto ldregs = [&](int kc) {
    ra0 = *(const f32x4*)(x32 + (size_t)(t0 + t_a) * 256 + kc + ka);
    ra1 = *(const f32x4*)(x32 + (size_t)(t0 + t_a) * 256 + kc + ka + 4);
    rb0 = *(const f32x4*)(qc_w + (size_t)(d0 + d_b) * 256 + kc + kb);
    rb1 = *(const f32x4*)(qc_w + (size_t)(d0 + d_b) * 256 + kc + kb + 4);
    rb2 = *(const f32x4*)(qc_w + (size_t)(d0 + d_b) * 256 + kc + kb + 8);
    rb3 = *(const f32x4*)(qc_w + (size_t)(d0 + d_b) * 256 + kc + kb + 12);
  };
  ldregs(0);

  f64x4 acc[4][2];
#pragma unroll
  for (int i = 0; i < 4; i++)
#pragma unroll
    for (int j = 0; j < 2; j++) acc[i][j] = (f64x4)0.0;

  for (int c = 0; c < 8; c++) {
    __syncthreads();
#pragma unroll
    for (int e = 0; e < 4; e++) {
      At[ka + e][t_a] = (double)ra0[e];
      At[ka + 4 + e][t_a] = (double)ra1[e];
      Bt[kb + e][d_b] = (double)rb0[e];
      Bt[kb + 4 + e][d_b] = (double)rb1[e];
      Bt[kb + 8 + e][d_b] = (double)rb2[e];
      Bt[kb + 12 + e][d_b] = (double)rb3[e];
    }
    __syncthreads();
    if (c < 7) ldregs((c + 1) * 32);
#pragma unroll
    for (int k4 = 0; k4 < 8; k4++) {
      int k = k4 * 4 + g;
      double a[4], b[2];
#pragma unroll
      for (int i = 0; i < 4; i++) a[i] = At[k][16 * i + cl];
#pragma unroll
      for (int j = 0; j < 2; j++) b[j] = Bt[k][32 * wid + 16 * j + cl];
#pragma unroll
      for (int i = 0; i < 4; i++)
#pragma unroll
        for (int j = 0; j < 2; j++)
          acc[i][j] = __builtin_amdgcn_mfma_f64_16x16x4f64(a[i], b[j], acc[i][j], 0, 0, 0);
    }
  }
#pragma unroll
  for (int i = 0; i < 4; i++)
#pragma unroll
    for (int j = 0; j < 2; j++) {
      int d = d0 + 32 * wid + 16 * j + cl;
      double bias = (double)qc_b[d];
#pragma unroll
      for (int r = 0; r < 4; r++) {
        int row = use_alt ? (g + 4 * r) : (4 * g + r);
        int t = t0 + 16 * i + row;
        h64[(size_t)t * 2048 + d] = acc[i][j][r] + bias;
      }
    }
}

// ---------------- fallback proj (proj2b VERIFIED r8-r13) — runs only if self-test tripped ----------------
__global__ __launch_bounds__(256) void k_proj_fb(const float* x32, const float* qc_w, const float* qc_b,
                                                 double* h64, const int* bad) {
  if (*bad == 0) return;
  __shared__ double At[16][128];
  __shared__ double Bt[16][16][9];
  int t0 = blockIdx.y * 128, d0 = blockIdx.x * 128;
  int tid = threadIdx.x;
  int tr = tid >> 4, dc = tid & 15;
  int srow = tid & 127, kh = (tid >> 7) * 8;
  int sg = srow >> 3, se = srow & 7;
  const float* pA = x32 + (size_t)(t0 + srow) * 256 + kh;
  const float* pB = qc_w + (size_t)(d0 + srow) * 256 + kh;
  f32x4 a0 = *(const f32x4*)pA, a1 = *(const f32x4*)(pA + 4);
  f32x4 b0 = *(const f32x4*)pB, b1 = *(const f32x4*)(pB + 4);
  double acc[8][8] = {};
  for (int kk = 0; kk < 256; kk += 16) {
    __syncthreads();
#pragma unroll
    for (int j = 0; j < 4; j++) {
      At[kh + j][srow] = (double)a0[j]; At[kh + 4 + j][srow] = (double)a1[j];
      Bt[kh + j][sg][se] = (double)b0[j]; Bt[kh + 4 + j][sg][se] = (double)b1[j];
    }
    __syncthreads();
    if (kk + 16 < 256) {
      a0 = *(const f32x4*)(pA + kk + 16); a1 = *(const f32x4*)(pA + kk + 20);
      b0 = *(const f32x4*)(pB + kk + 16); b1 = *(const f32x4*)(pB + kk + 20);
    }
#pragma unroll
    for (int k = 0; k < 16; k++) {
      double a[8], b[8];
#pragma unroll
      for (int j = 0; j < 8; j++) a[j] = At[k][tr * 8 + j];
#pragma unroll
      for (int j = 0; j < 8; j++) b[j] = Bt[k][dc][j];
#pragma unroll
      for (int i = 0; i < 8; i++)
#pragma unroll
        for (int j = 0; j < 8; j++)
          acc[i][j] = fma(a[i], b[j], acc[i][j]);
    }
  }
#pragma unroll
  for (int i = 0; i < 8; i++)
#pragma unroll
    for (int j = 0; j < 8; j++) {
      int col = d0 + dc * 8 + j;
      h64[(size_t)(t0 + tr * 8 + i) * 2048 + col] = acc[i][j] + (double)qc_b[col];
    }
}

// ---------------- P' GEMM fused with codebook norms (VERIFIED r7-r16) ----------------
__global__ __launch_bounds__(256) void k_pgemm4(const float* cb, const f16* wT, f16* P16kt,
                                                double* inv64, float* inv32) {
  __shared__ f16 Al[2][64][32];
  __shared__ f16 Bl[2][160][32];
  __shared__ double nsum[64][4];
  __shared__ double invsh[64];
  int j0 = blockIdx.x * 64;
  int c0 = blockIdx.y * 160;
  int tid = threadIdx.x, wid = tid >> 6, lane = tid & 63;
  int cl = lane & 15, g = lane >> 4;
  f32x4 acc[10];
#pragma unroll
  for (int n = 0; n < 10; n++) acc[n] = (f32x4)0.0f;
  int arow = tid & 63, aseg = tid >> 6;
  double s2 = 0.0;

  auto aload = [&](int kk, f32x4& v0, f32x4& v1) {
    v0 = *(const f32x4*)(cb + (size_t)(j0 + arow) * 2048 + kk + aseg * 8);
    v1 = *(const f32x4*)(cb + (size_t)(j0 + arow) * 2048 + kk + aseg * 8 + 4);
  };
  auto addnorm = [&](f32x4 v0, f32x4 v1) {
#pragma unroll
    for (int e = 0; e < 4; e++) {
      s2 += (double)v0[e] * (double)v0[e];
      s2 += (double)v1[e] * (double)v1[e];
    }
  };
  auto awrite = [&](int buf, f32x4 v0, f32x4 v1) {
    f16x8 h;
#pragma unroll
    for (int e = 0; e < 4; e++) { h[e] = (f16)v0[e]; h[4 + e] = (f16)v1[e]; }
    int sp = aseg ^ ((arow >> 1) & 3);
    *(f16x8*)((char*)&Al[buf][arow][0] + sp * 16) = h;
  };
  auto stageB = [&](int kk, int buf) {
#pragma unroll
    for (int i = 0; i < 3; i++) {
      int g2 = wid + 4 * i;
      if (g2 < 10) {
        int r0 = 16 * g2;
        int rl = r0 + (lane >> 2);
        int sl = (lane & 3) ^ ((rl >> 1) & 3);
        gload_lds16(wT + (size_t)(c0 + rl) * 2048 + kk + sl * 8, &Bl[buf][r0][0]);
      }
    }
  };
  auto rdA = [&](int buf, int r, int sg2) -> f16x8 {
    return *(const f16x8*)((const char*)&Al[buf][0][0] + r * 64 + ((sg2 ^ ((r >> 1) & 3)) << 4));
  };
  auto rdB = [&](int buf, int r, int sg2) -> f16x8 {
    return *(const f16x8*)((const char*)&Bl[buf][0][0] + r * 64 + ((sg2 ^ ((r >> 1) & 3)) << 4));
  };

  { f32x4 v0, v1; aload(0, v0, v1); addnorm(v0, v1); awrite(0, v0, v1); }
  stageB(0, 0);
  asm volatile("s_waitcnt vmcnt(0)" ::: "memory");
  __syncthreads();
  for (int s = 0; s < 64; s++) {
    int buf = s & 1;
    f32x4 v0, v1;
    if (s < 63) { aload((s + 1) * 32, v0, v1); stageB((s + 1) * 32, buf ^ 1); }
    f16x8 av = rdA(buf, 16 * wid + cl, g);
#pragma unroll
    for (int n = 0; n < 10; n++) {
      f16x8 bv = rdB(buf, 16 * n + cl, g);
      acc[n] = __builtin_amdgcn_mfma_f32_16x16x32_f16(av, bv, acc[n], 0, 0, 0);
    }
    if (s < 63) { addnorm(v0, v1); awrite(buf ^ 1, v0, v1); }
    asm volatile("s_waitcnt vmcnt(0)" ::: "memory");
    __syncthreads();
  }
  nsum[arow][aseg] = s2;
  __syncthreads();
  if (tid < 64) {
    double t = nsum[tid][0] + nsum[tid][1] + nsum[tid][2] + nsum[tid][3];
    double nn = sqrt(t); nn = fmax(nn, 1e-12);
    double iv = 1.0 / nn;
    invsh[tid] = iv;
    if (blockIdx.y == 0) { inv64[j0 + tid] = iv; inv32[j0 + tid] = (float)iv; }
  }
  __syncthreads();
#pragma unroll
  for (int r = 0; r < 4; r++) {
    int rloc = 16 * wid + 4 * g + r;
    int row = j0 + rloc;
    float sc = (float)invsh[rloc];
#pragma unroll
    for (int n = 0; n < 10; n++) {
      int c = c0 + 16 * n + cl;
      int ks = c >> 5;
      int sl = ((c & 31) >> 3) ^ ((row >> 1) & 3);
      P16kt[(((size_t)ks * KCB + row) << 5) + (sl << 3) + (c & 7)] = (f16)(acc[n][r] * sc);
    }
  }
}

// ---------------- screen v11: 256x256 tile, 512 threads (8 waves 2x4), 3-buf depth-2 counted vmcnt ----------------
// Grid 1024, XCD swizzle: xcd = bid&7 owns code-blocks [8*xcd, 8*xcd+8).
__global__ __launch_bounds__(512) void k_screen11(const f16* x16, const f16* P16kt,
                                                  int* cnt, float* cand_v, int* cand_i) {
  __shared__ f16 Al[3][256][32];
  __shared__ f16 Bl[3][256][32];
  __shared__ float smx[256][4];
  int bid = blockIdx.x;
  int nb = ((bid & 7) << 3) | ((bid >> 3) & 7);    // code-block 0..63 (256 codes each)
  int tb = bid >> 6;                                // token-block 0..15 (256 tokens each)
  int n0 = nb * 256, t0 = tb * 256;
  int tid = threadIdx.x, wid = tid >> 6, lane = tid & 63;
  int wr = wid >> 2, wc = wid & 3;                  // 2 x 4 wave grid; wave tile 128 x 64
  int cl = lane & 15, g = lane >> 4;
  f32x4 acc[8][4];
#pragma unroll
  for (int m = 0; m < 8; m++)
#pragma unroll
    for (int n = 0; n < 4; n++) acc[m][n] = (f32x4)0.0f;

  auto stageA = [&](int ks, int buf) {
#pragma unroll
    for (int i = 0; i < 2; i++) {
      int r0 = 32 * wid + 16 * i;
      int rl = r0 + (lane >> 2);
      int sl = (lane & 3) ^ ((rl >> 1) & 3);
      gload_lds16(x16 + (size_t)(t0 + rl) * 320 + ks * 32 + sl * 8, &Al[buf][r0][0]);
    }
  };
  auto stageB = [&](int ks, int buf) {
    const f16* src = P16kt + (((size_t)ks * KCB + n0) << 5) + wid * 1024 + lane * 8;
    gload_lds16(src, &Bl[buf][wid * 32][0]);
    gload_lds16(src + 512, &Bl[buf][wid * 32 + 16][0]);
  };
  auto rdA = [&](int buf, int r, int sg) -> f16x8 {
    return *(const f16x8*)((const char*)&Al[buf][0][0] + r * 64 + ((sg ^ ((r >> 1) & 3)) << 4));
  };
  auto rdB = [&](int buf, int r, int sg) -> f16x8 {
    return *(const f16x8*)((const char*)&Bl[buf][0][0] + r * 64 + ((sg ^ ((r >> 1) & 3)) << 4));
  };

  // depth-2 prologue
  stageA(0, 0); stageB(0, 0);
  stageA(1, 1); stageB(1, 1);
#pragma unroll
  for (int s = 0; s < 10; s++) {
    const int buf = s % 3;
    if (s <= 8) asm volatile("s_waitcnt vmcnt(4)" ::: "memory");
    else        asm volatile("s_waitcnt vmcnt(0)" ::: "memory");
    __builtin_amdgcn_s_barrier();
    __builtin_amdgcn_sched_barrier(0);
    f16x8 av[8], bv[4];
#pragma unroll
    for (int m = 0; m < 8; m++) av[m] = rdA(buf, 128 * wr + 16 * m + cl, g);
#pragma unroll
    for (int n = 0; n < 4; n++) bv[n] = rdB(buf, 64 * wc + 16 * n + cl, g);
    __builtin_amdgcn_s_setprio(1);
#pragma unroll
    for (int m = 0; m < 8; m++)
#pragma unroll
      for (int n = 0; n < 4; n++)
        acc[m][n] = __builtin_amdgcn_mfma_f32_16x16x32_f16(av[m], bv[n], acc[m][n], 0, 0, 0);
    __builtin_amdgcn_s_setprio(0);
    if (s + 2 < 10) {
      const int nb2 = (s + 2) % 3;
      stageA(s + 2, nb2); stageB(s + 2, nb2);
    }
  }

  // ---- epilogue phase 1: block-local row max (per wave-col partial, then combined)
#pragma unroll
  for (int m = 0; m < 8; m++) {
#pragma unroll
    for (int r = 0; r < 4; r++) {
      float v = -3.4e38f;
#pragma unroll
      for (int n = 0; n < 4; n++) v = fmaxf(v, acc[m][n][r]);
      v = fmaxf(v, __shfl_xor(v, 1));
      v = fmaxf(v, __shfl_xor(v, 2));
      v = fmaxf(v, __shfl_xor(v, 4));
      v = fmaxf(v, __shfl_xor(v, 8));
      if (cl == 0) smx[128 * wr + 16 * m + 4 * g + r][wc] = v;
    }
  }
  __syncthreads();

  // ---- epilogue phase 2: LDS-compacted collection (overlay on dead Al buffer)
  uint32_t* lcnt = (uint32_t*)(&Al[0][0][0]);       // 256 u32
  float*    lval = (float*)(lcnt + 256);            // 256*MAXL f32
  int*      lidx = (int*)(lval + 256 * MAXL);       // 256*MAXL i32
  if (tid < 256) lcnt[tid] = 0;
  __syncthreads();

#pragma unroll
  for (int m = 0; m < 8; m++) {
#pragma unroll
    for (int r = 0; r < 4; r++) {
      int rloc = 128 * wr + 16 * m + 4 * g + r;
      float lim = fmaxf(fmaxf(smx[rloc][0], smx[rloc][1]), fmaxf(smx[rloc][2], smx[rloc][3])) - MARGIN_C;
#pragma unroll
      for (int n = 0; n < 4; n++) {
        float vv = acc[m][n][r];
        if (vv >= lim) {
          uint32_t p = atomicAdd(&lcnt[rloc], 1u);
          int code = n0 + 64 * wc + 16 * n + cl;
          if (p < MAXL) { lval[rloc * MAXL + p] = vv; lidx[rloc * MAXL + p] = code; }
          else {
            int slot = atomicAdd(&cnt[t0 + rloc], 1);
            if (slot < CAP) { cand_v[(t0 + rloc) * CAP + slot] = vv; cand_i[(t0 + rloc) * CAP + slot] = code; }
          }
        }
      }
    }
  }
  __syncthreads();

  // ---- epilogue phase 3: one global atomic per row, bulk copy
  if (tid < 256) {
    int lc = (int)lcnt[tid]; if (lc > MAXL) lc = MAXL;
    if (lc > 0) {
      int row = t0 + tid;
      int base = atomicAdd(&cnt[row], lc);
      for (int i = 0; i < lc; i++) {
        int slot = base + i;
        if (slot < CAP) {
          cand_v[row * CAP + slot] = lval[tid * MAXL + i];
          cand_i[row * CAP + slot] = lidx[tid * MAXL + i];
        }
      }
    }
  }
}

// ---------------- rescore v3: one wave per token, no LDS / no barriers (VERIFIED r14/r15) ----------------
__global__ __launch_bounds__(64) void k_rescore3(const double* h64, const float* cb, const double* inv64,
                                                 const int* cnt, const float* cand_v, const int* cand_i,
                                                 float* idxf, int* idxi) {
  int t = blockIdx.x;
  int lane = threadIdx.x;
  int ctot = cnt[t];
  double bV = -1e300; int bI = 0x7fffffff;
  const double* hrow = h64 + (size_t)t * 2048;
  if (ctot <= CAP) {
    float gm = -3.4e38f;
    for (int c = lane; c < ctot; c += 64) gm = fmaxf(gm, cand_v[t * CAP + c]);
#pragma unroll
    for (int o = 32; o; o >>= 1) gm = fmaxf(gm, __shfl_xor(gm, o));
    float lim = gm - MARGIN_F;
    for (int c = 0; c < ctot; c++) {
      float v = cand_v[t * CAP + c];
      if (v < lim) continue;
      int code = cand_i[t * CAP + c];
      const float* crow = cb + (size_t)code * 2048;
      double p = 0.0;
#pragma unroll
      for (int e = 0; e < 32; e++) {
        int d = lane + 64 * e;
        p = fma(hrow[d], (double)crow[d], p);
      }
#pragma unroll
      for (int o = 32; o; o >>= 1) p += __shfl_xor(p, o);
      double sv = p * inv64[code];
      if (sv > bV || (sv == bV && code < bI)) { bV = sv; bI = code; }
    }
  } else {
    for (int code = 0; code < KCB; code++) {
      const float* crow = cb + (size_t)code * 2048;
      double p = 0.0;
      for (int e = 0; e < 32; e++) {
        int d = lane + 64 * e;
        p = fma(hrow[d], (double)crow[d], p);
      }
      for (int o = 32; o; o >>= 1) p += __shfl_xor(p, o);
      double sv = p * inv64[code];
      if (sv > bV || (sv == bV && code < bI)) { bV = sv; bI = code; }
    }
  }
  if (lane == 0) { idxi[t] = bI; idxf[t] = (float)bI; }
}

// ---------------- gather quant output ----------------
__global__ __launch_bounds__(256) void k_quant(const float* cb, const float* inv32, const int* idxi, float* out0) {
  int hw = blockIdx.x * 256 + threadIdx.x;
  int d = blockIdx.y, b = blockIdx.z;
  int t = b * 1024 + hw;
  int row = idxi[t];
  out0[((size_t)b * 2048 + d) * 1024 + hw] = cb[(size_t)row * 2048 + d] * inv32[row];
}

extern "C" void kernel_launch(void* const* d_in, const int* in_sizes, int n_in,
                              void* d_out, int out_size, void* d_ws, size_t ws_size,
                              hipStream_t stream) {
  const float* hid = (const float*)d_in[0];
  const float* cb  = (const float*)d_in[1];
  const float* qw  = (const float*)d_in[2];
  const float* qb  = (const float*)d_in[3];
  float* out = (float*)d_out;  // [4*2048*1024 quant][4096 idx-as-float]

  char* w = (char*)d_ws;
  size_t off = 0;
  auto alloc = [&](size_t bytes) -> void* {
    void* p = w + off;
    off += (bytes + 255) & ~(size_t)255;
    return p;
  };
  double* h64   = (double*)alloc((size_t)NTOK * 2048 * 8);
  f16*    x16   = (f16*)   alloc((size_t)NTOK * 320 * 2);
  float*  x32   = (float*) alloc((size_t)NTOK * 256 * 4);
  f16*    wT    = (f16*)   alloc((size_t)320 * 2048 * 2);
  f16*    P16kt = (f16*)   alloc((size_t)10 * KCB * 32 * 2);
  double* inv64 = (double*)alloc((size_t)KCB * 8);
  float*  inv32 = (float*) alloc((size_t)KCB * 4);
  int*    cnt   = (int*)   alloc((size_t)NTOK * 4);
  float*  cand_v= (float*) alloc((size_t)NTOK * CAP * 4);
  int*    cand_i= (int*)   alloc((size_t)NTOK * CAP * 4);
  int*    idxi  = (int*)   alloc((size_t)NTOK * 4);
  int*    bad   = (int*)   alloc(256);

  k_init<<<16, 256, 0, stream>>>(cnt, bad);
  k_build_wT<<<dim3(32, 5), 256, 0, stream>>>(qw, qb, wT);
  k_build_x<<<dim3(16, 4, 4), 256, 0, stream>>>(hid, x16, x32);
  k_proj_mfma<<<dim3(16, 64), 256, 0, stream>>>(x32, qw, qb, h64, bad);
  k_proj_fb<<<dim3(16, 32), 256, 0, stream>>>(x32, qw, qb, h64, bad);
  k_pgemm4<<<dim3(256, 2), 256, 0, stream>>>(cb, wT, P16kt, inv64, inv32);
  k_screen11<<<1024, 512, 0, stream>>>(x16, P16kt, cnt, cand_v, cand_i);
  k_rescore3<<<NTOK, 64, 0, stream>>>(h64, cb, inv64, cnt, cand_v, cand_i, out + 8388608, idxi);
  k_quant<<<dim3(4, 2048, 4), 256, 0, stream>>>(cb, inv32, idxi, out);
}